// Round 7
// baseline (249.165 us; speedup 1.0000x reference)
//
#include <hip/hip_runtime.h>
#include <hip/hip_bf16.h>
#include <math.h>

#define BB 64
#define TT 512
#define IW 256
#define HH 512
#define G3H 1536

__device__ __forceinline__ double dshfl_xor(double v, int m){
  int2 a = *(int2*)&v;
  a.x = __shfl_xor(a.x, m, 64);
  a.y = __shfl_xor(a.y, m, 64);
  return *(double*)&a;
}

__global__ void sentinel_k(float* out, float v){ out[0] = v; }

// ---------- prep: transpose x0 (blocks 0..63) + colsum Wl (blocks 64..71) ----------
__global__ __launch_bounds__(256) void prep(const float* __restrict__ x, float* __restrict__ x0T,
                                            const float* __restrict__ Wl, double* __restrict__ w_d){
  if (blockIdx.x < 64){
    int idx = blockIdx.x*256 + threadIdx.x;          // [0, 16384)
    int b = idx >> 8, i = idx & 255;
    x0T[i*64 + b] = x[(size_t)b*TT*IW + i];          // x[b][0][i]
  } else {
    __shared__ double part[4][64];
    int lane = threadIdx.x & 63, ty = threadIdx.x >> 6;
    int h = (blockIdx.x - 64)*64 + lane;
    double acc = 0.0;
    for (int j = ty*128; j < ty*128 + 128; ++j) acc += (double)Wl[(size_t)j*HH + h];
    part[ty][lane] = acc;
    __syncthreads();
    if (ty == 0) w_d[h] = part[0][lane] + part[1][lane] + part[2][lane] + part[3][lane];
  }
}

// ---------- fused gates GEMM + GRU activation ----------
// block: one s, 8 h-values; rows staged: {r,z,n} x 8 = 24 rows of K
// in: [s][K][64] (x0T has s-stride 0); writes h_all[s][b][l][h], hT_out[s][h][b]
template<int K>
__global__ __launch_bounds__(256) void gru_fused(const float* __restrict__ W, long wS,
                                                 const float* __restrict__ bih, long bihS,
                                                 const float* __restrict__ bhh, long bhhS,
                                                 const float* __restrict__ in, int inS,
                                                 float* __restrict__ h_all,
                                                 float* __restrict__ hT_out, int writeHT, int l){
  __shared__ float wlds[24][K];
  const int K4 = K/4;
  int tid = threadIdx.x;
  int lane = tid & 63, wv = tid >> 6;
  int s  = blockIdx.x >> 6;
  int h0 = (blockIdx.x & 63) * 8;
  const float4* Wp = (const float4*)(W + (size_t)s*wS);
  for (int q = tid; q < 24*K4; q += 256){
    int r = q / K4, i4 = q % K4;
    *(float4*)&wlds[r][i4*4] = Wp[((size_t)(r>>3)*512 + h0 + (r&7))*K4 + i4];
  }
  __syncthreads();
  const float* xp = in + (size_t)s*inS + lane;
  int j = wv*2;
  float r0=0.f,z0=0.f,n0=0.f, r1=0.f,z1=0.f,n1=0.f;
  #pragma unroll 4
  for (int k = 0; k < K; ++k){
    float xv = xp[(size_t)k*64];
    r0 += wlds[j   ][k]*xv;  z0 += wlds[8+j ][k]*xv;  n0 += wlds[16+j ][k]*xv;
    r1 += wlds[j+1 ][k]*xv;  z1 += wlds[9+j ][k]*xv;  n1 += wlds[17+j ][k]*xv;
  }
  const float* bi = bih + (size_t)s*bihS;
  const float* bh = bhh + (size_t)s*bhhS;
  int b = lane;
  #pragma unroll
  for (int u = 0; u < 2; ++u){
    int h = h0 + j + u;
    float gr = (u ? r1 : r0) + bi[h]      + bh[h];
    float gz = (u ? z1 : z0) + bi[512+h]  + bh[512+h];
    float gn = (u ? n1 : n0) + bi[1024+h];
    float rr = 1.f/(1.f + expf(-gr));
    float zz = 1.f/(1.f + expf(-gz));
    float nn = tanhf(gn + rr*bh[1024+h]);
    float hv = (1.f - zz)*nn;
    h_all[(((size_t)s*BB + b)*3 + l)*HH + h] = hv;
    if (writeHT) hT_out[((size_t)s*HH + h)*BB + b] = hv;
  }
}

// ---------- dots + fold fused: block s (3 blocks, 192 threads) ----------
__global__ __launch_bounds__(192) void dots_fold(const float* __restrict__ h_all,
                                                 const double* __restrict__ w_d,
                                                 const float* __restrict__ Ws,
                                                 const float* __restrict__ bs,
                                                 double* __restrict__ P1){
  __shared__ double scoreL[192];
  __shared__ double dmatL[192][3];
  int s = blockIdx.x, q = threadIdx.x;             // q = b*3 + l
  const float* hp = h_all + ((size_t)s*192 + q)*HH;
  double a0=0.0, a1=0.0, a2=0.0, a3=0.0;
  for (int h = 0; h < HH; ++h){
    double hv = (double)hp[h];
    a0 += hv * w_d[h];
    a1 += hv * (double)Ws[h];
    a2 += hv * (double)Ws[768 + h];
    a3 += hv * (double)Ws[1536 + h];
  }
  scoreL[q] = a0; dmatL[q][0] = a1; dmatL[q][1] = a2; dmatL[q][2] = a3;
  __syncthreads();
  int b = q & 63, c = q >> 6;
  int base = b*3;
  double s0 = scoreL[base], s1 = scoreL[base+1], s2 = scoreL[base+2];
  double m = fmax(s0, fmax(s1, s2));
  double e0 = exp(s0-m), e1 = exp(s1-m), e2 = exp(s2-m);
  double inv = 1.0/(e0+e1+e2);
  e0 *= inv; e1 *= inv; e2 *= inv;
  double v = e0*dmatL[base][c] + e1*dmatL[base+1][c] + e2*dmatL[base+2][c];
  P1[(s*3 + c)*64 + b] = v + (double)bs[c];
}

// ---------- fused xdot + softmax-sums: block t, 192 threads ----------
// Lint[t][cur*3+c] = round( log2( sum_b softmax_c(P1[cur]+D[t])[b] ) * 2^20 ), stride 12
__global__ __launch_bounds__(192) void sums_x(const float* __restrict__ x,
                                              const float* __restrict__ Ws,
                                              const double* __restrict__ P1,
                                              int* __restrict__ Lint){
  __shared__ float xl[64*257];
  __shared__ float wsl[3*256];
  __shared__ double dl[3*64];
  int t = blockIdx.x, tid = threadIdx.x;
  int lane = tid & 63, w = tid >> 6;               // w = c (phase1) / cur (phase2)
  for (int i = tid; i < 768; i += 192) wsl[i] = Ws[(i >> 8)*768 + 512 + (i & 255)];
  for (int q = tid; q < 4096; q += 192){           // stage x[:,t,:] via float4
    int r = q >> 6, i4 = q & 63;
    float4 v = *(const float4*)(x + ((size_t)r*TT + t)*IW + i4*4);
    float* dst = &xl[r*257 + i4*4];
    dst[0]=v.x; dst[1]=v.y; dst[2]=v.z; dst[3]=v.w;
  }
  __syncthreads();
  {
    const float* xr = &xl[lane*257];
    const float* wr = &wsl[w*256];
    double acc = 0.0;
    #pragma unroll 8
    for (int i = 0; i < 256; ++i) acc += (double)xr[i] * (double)wr[i];
    dl[w*64 + lane] = acc;
  }
  __syncthreads();
  double l0 = P1[(w*3+0)*64 + lane] + dl[0*64 + lane];
  double l1 = P1[(w*3+1)*64 + lane] + dl[1*64 + lane];
  double l2 = P1[(w*3+2)*64 + lane] + dl[2*64 + lane];
  double m = fmax(l0, fmax(l1, l2));
  double e0 = exp(l0-m), e1 = exp(l1-m), e2 = exp(l2-m);
  double inv = 1.0/(e0+e1+e2);
  e0 *= inv; e1 *= inv; e2 *= inv;
  for (int mm = 32; mm; mm >>= 1){
    e0 += dshfl_xor(e0, mm); e1 += dshfl_xor(e1, mm); e2 += dshfl_xor(e2, mm);
  }
  if (lane == 0){
    int* p = Lint + (size_t)t*12 + w*3;
    p[0] = (int)lrintf(fmaxf(log2f((float)e0), -1500.f) * 1048576.0f);
    p[1] = (int)lrintf(fmaxf(log2f((float)e1), -1500.f) * 1048576.0f);
    p[2] = (int)lrintf(fmaxf(log2f((float)e2), -1500.f) * 1048576.0f);
  }
}

// ---------- scalar-unit scan: integer fixed-point, SGPR chain ----------
__device__ __forceinline__ int imin3(int a, int b, int c){
  int m = a < b ? a : b; return m < c ? m : c;
}

__global__ __launch_bounds__(64) void scan5(const int* __restrict__ Lint,
                                            unsigned* __restrict__ curpack){
  __shared__ int lds[TT*12];
  int lane = threadIdx.x;
  for (int i = lane*4; i < TT*12; i += 256)
    *(int4*)&lds[i] = *(const int4*)&Lint[i];
  __syncthreads();
  int a0 = 1<<20, a1 = 0, a2 = 0;   // pen = [0.5,1,1] -> exponents [1,0,0] (x 2^20)
  int cur = 0;
  for (int g = 0; g < 32; ++g){
    unsigned word = 0u;
    #pragma unroll
    for (int k = 0; k < 16; ++k){
      int t = g*16 + k;
      if (g == 0 && k == 0) continue;            // t=0: cur=0 (bits already 0)
      const int* p = &lds[t*12];
      int x0 = __builtin_amdgcn_readfirstlane(p[0]);
      int x1 = __builtin_amdgcn_readfirstlane(p[1]);
      int x2 = __builtin_amdgcn_readfirstlane(p[2]);
      int x3 = __builtin_amdgcn_readfirstlane(p[3]);
      int x4 = __builtin_amdgcn_readfirstlane(p[4]);
      int x5 = __builtin_amdgcn_readfirstlane(p[5]);
      int x6 = __builtin_amdgcn_readfirstlane(p[6]);
      int x7 = __builtin_amdgcn_readfirstlane(p[7]);
      int x8 = __builtin_amdgcn_readfirstlane(p[8]);
      int L0 = (cur==0) ? x0 : ((cur==1) ? x3 : x6);
      int L1 = (cur==0) ? x1 : ((cur==1) ? x4 : x7);
      int L2 = (cur==0) ? x2 : ((cur==1) ? x5 : x8);
      int v0 = L0 - a0, v1 = L1 - a1, v2 = L2 - a2;
      int best = v0, c = 0;
      if (v1 > best){ best = v1; c = 1; }
      if (v2 > best){ c = 2; }
      cur = c;
      a0 += (c==0) ? (1<<20) : 0;
      a1 += (c==1) ? (1<<20) : 0;
      a2 += (c==2) ? (1<<20) : 0;
      int mn = imin3(a0, a1, a2);
      a0 -= mn; a1 -= mn; a2 -= mn;
      word |= (unsigned)c << (2*k);
    }
    if (lane == 0) curpack[g] = word;
  }
}

// ---------- outputs (f32), fused; cur from 2-bit packed words ----------
__global__ __launch_bounds__(256) void out_all(const float* __restrict__ h_all,
                                               const unsigned* __restrict__ curpack,
                                               float* __restrict__ out){
  int blk = blockIdx.x;
  if (blk < 512){
    int t = blk;
    int cur = (int)((curpack[t >> 4] >> ((t & 15)*2)) & 3u);
    const float* base = h_all + (size_t)cur*98304 + 2*HH;  // [cur][b][2][:], b-stride 1536
    int tid = threadIdx.x;
    for (int k = 0; k < 32; ++k){
      int e4 = (k*256 + tid)*4;                            // [0, 32768)
      int b = e4 >> 9, h = e4 & 511;
      float4 v = *(const float4*)(base + (size_t)b*1536 + h);
      *(float4*)(&out[((size_t)b*TT + t)*HH + h]) = v;
    }
  } else {
    int cur = (int)((curpack[31] >> 30) & 3u);
    int e4 = ((blk - 512)*256 + threadIdx.x)*4;            // [0, 98304)
    float4 v = *(const float4*)(h_all + (size_t)cur*98304 + e4);
    *(float4*)(&out[(size_t)BB*TT*HH + e4]) = v;
  }
}

extern "C" void kernel_launch(void* const* d_in, const int* in_sizes, int n_in,
                              void* d_out, int out_size, void* d_ws, size_t ws_size,
                              hipStream_t stream){
  const float* x    = (const float*)d_in[0];
  const float* Wl   = (const float*)d_in[1];
  // d_in[2] = bl : constant over L inside softmax -> cancels; unused
  const float* Ws   = (const float*)d_in[3];
  const float* bs   = (const float*)d_in[4];
  const float* Wih0 = (const float*)d_in[5];
  const float* bih0 = (const float*)d_in[6];
  const float* bhh0 = (const float*)d_in[7];
  const float* WihL = (const float*)d_in[8];
  const float* bihL = (const float*)d_in[9];
  const float* bhhL = (const float*)d_in[10];
  float* out = (float*)d_out;

  // ---- sentinels ----
  static const int exp_sizes[11] = {8388608, 262144, 512, 2304, 3,
                                    1179648, 4608, 4608, 4718592, 9216, 9216};
  int bad = 0;
  if (n_in != 11) bad = 13;
  else {
    for (int i = 0; i < 11; ++i) if (in_sizes[i] != exp_sizes[i]) { bad = i + 1; break; }
  }
  if (!bad && out_size != 16875520) bad = 12;
  if (bad){
    sentinel_k<<<dim3(1), dim3(1), 0, stream>>>(out, 1048576.0f * (float)bad);
    return;
  }
  if (ws_size < 1278592){
    sentinel_k<<<dim3(1), dim3(1), 0, stream>>>(out, 3.0e7f + (float)(ws_size >> 6));
    return;
  }

  // ---- ws layout (1,278,592 B) ----
  double*   w_d     = (double*)d_ws;              // 512 f64
  double*   P1      = w_d + 512;                  // 576 f64
  int*      Lint    = (int*)(P1 + 576);           // 512*12 i32
  float*    h_all   = (float*)(Lint + 6144);      // 294912 f32
  float*    x0T     = h_all + 294912;             // 16384 f32
  unsigned* curpack = (unsigned*)(x0T + 16384);   // 32 u32

  // ---- hT double-buffer in d_out tail (dead before out_all writes) ----
  char* outb = (char*)d_out;
  float* hT0 = (float*)(outb + 50331648);         // [3][512][64] f32 = 393,216 B
  float* hT1 = hT0 + 98304;                       // same

  prep<<<dim3(72), dim3(256), 0, stream>>>(x, x0T, Wl, w_d);

  // fused GRU stack
  gru_fused<256><<<dim3(192), dim3(256), 0, stream>>>(
      Wih0, (long)G3H*IW, bih0, G3H, bhh0, G3H, x0T, 0, h_all, hT0, 1, 0);
  gru_fused<512><<<dim3(192), dim3(256), 0, stream>>>(
      WihL, (long)2*G3H*HH, bihL, 2*G3H, bhhL, 2*G3H, hT0, HH*BB, h_all, hT1, 1, 1);
  gru_fused<512><<<dim3(192), dim3(256), 0, stream>>>(
      WihL + (size_t)G3H*HH, (long)2*G3H*HH, bihL + G3H, 2*G3H, bhhL + G3H, 2*G3H,
      hT1, HH*BB, h_all, hT0, 0, 2);

  dots_fold<<<dim3(3),   dim3(192), 0, stream>>>(h_all, w_d, Ws, bs, P1);
  sums_x   <<<dim3(512), dim3(192), 0, stream>>>(x, Ws, P1, Lint);

  scan5<<<dim3(1), dim3(64), 0, stream>>>(Lint, curpack);

  out_all<<<dim3(608), dim3(256), 0, stream>>>(h_all, curpack, out);
}

// Round 8
// 193.031 us; speedup vs baseline: 1.2908x; 1.2908x over previous
//
#include <hip/hip_runtime.h>
#include <hip/hip_bf16.h>
#include <math.h>

#define BB 64
#define TT 512
#define IW 256
#define HH 512
#define G3H 1536
#define PEN1 (1<<20)

__device__ __forceinline__ double dshfl_xor(double v, int m){
  int2 a = *(int2*)&v;
  a.x = __shfl_xor(a.x, m, 64);
  a.y = __shfl_xor(a.y, m, 64);
  return *(double*)&a;
}

__global__ void sentinel_k(float* out, float v){ out[0] = v; }

// ---------- prep: transpose x0 (blocks 0..63) + colsum Wl (blocks 64..71) ----------
__global__ __launch_bounds__(256) void prep(const float* __restrict__ x, float* __restrict__ x0T,
                                            const float* __restrict__ Wl, double* __restrict__ w_d){
  if (blockIdx.x < 64){
    int idx = blockIdx.x*256 + threadIdx.x;          // [0, 16384)
    int b = idx >> 8, i = idx & 255;
    x0T[i*64 + b] = x[(size_t)b*TT*IW + i];          // x[b][0][i]
  } else {
    __shared__ double part[4][64];
    int lane = threadIdx.x & 63, ty = threadIdx.x >> 6;
    int h = (blockIdx.x - 64)*64 + lane;
    double acc = 0.0;
    for (int j = ty*128; j < ty*128 + 128; ++j) acc += (double)Wl[(size_t)j*HH + h];
    part[ty][lane] = acc;
    __syncthreads();
    if (ty == 0) w_d[h] = part[0][lane] + part[1][lane] + part[2][lane] + part[3][lane];
  }
}

// ---------- fused gates GEMM + GRU activation (float4 weight reads) ----------
template<int K>
__global__ __launch_bounds__(256) void gru_fused(const float* __restrict__ W, long wS,
                                                 const float* __restrict__ bih, long bihS,
                                                 const float* __restrict__ bhh, long bhhS,
                                                 const float* __restrict__ in, int inS,
                                                 float* __restrict__ h_all,
                                                 float* __restrict__ hT_out, int writeHT, int l){
  __shared__ float wlds[24][K];
  const int K4 = K/4;
  int tid = threadIdx.x;
  int lane = tid & 63, wv = tid >> 6;
  int s  = blockIdx.x >> 6;
  int h0 = (blockIdx.x & 63) * 8;
  const float4* Wp = (const float4*)(W + (size_t)s*wS);
  for (int q = tid; q < 24*K4; q += 256){
    int r = q / K4, i4 = q % K4;
    *(float4*)&wlds[r][i4*4] = Wp[((size_t)(r>>3)*512 + h0 + (r&7))*K4 + i4];
  }
  __syncthreads();
  const float* xp = in + (size_t)s*inS + lane;
  int j = wv*2;
  const float4* wr0 = (const float4*)wlds[j];
  const float4* wr1 = (const float4*)wlds[j+1];
  const float4* wz0 = (const float4*)wlds[8+j];
  const float4* wz1 = (const float4*)wlds[9+j];
  const float4* wn0 = (const float4*)wlds[16+j];
  const float4* wn1 = (const float4*)wlds[17+j];
  float r0=0.f,z0=0.f,n0=0.f, r1=0.f,z1=0.f,n1=0.f;
  #pragma unroll 4
  for (int k4 = 0; k4 < K4; ++k4){
    float xv0 = xp[(k4*4+0)*64];
    float xv1 = xp[(k4*4+1)*64];
    float xv2 = xp[(k4*4+2)*64];
    float xv3 = xp[(k4*4+3)*64];
    float4 wa = wr0[k4], wb = wr1[k4], wc = wz0[k4], wd = wz1[k4], we = wn0[k4], wf = wn1[k4];
    r0 += wa.x*xv0 + wa.y*xv1 + wa.z*xv2 + wa.w*xv3;
    r1 += wb.x*xv0 + wb.y*xv1 + wb.z*xv2 + wb.w*xv3;
    z0 += wc.x*xv0 + wc.y*xv1 + wc.z*xv2 + wc.w*xv3;
    z1 += wd.x*xv0 + wd.y*xv1 + wd.z*xv2 + wd.w*xv3;
    n0 += we.x*xv0 + we.y*xv1 + we.z*xv2 + we.w*xv3;
    n1 += wf.x*xv0 + wf.y*xv1 + wf.z*xv2 + wf.w*xv3;
  }
  const float* bi = bih + (size_t)s*bihS;
  const float* bh = bhh + (size_t)s*bhhS;
  int b = lane;
  #pragma unroll
  for (int u = 0; u < 2; ++u){
    int h = h0 + j + u;
    float gr = (u ? r1 : r0) + bi[h]      + bh[h];
    float gz = (u ? z1 : z0) + bi[512+h]  + bh[512+h];
    float gn = (u ? n1 : n0) + bi[1024+h];
    float rr = 1.f/(1.f + expf(-gr));
    float zz = 1.f/(1.f + expf(-gz));
    float nn = tanhf(gn + rr*bh[1024+h]);
    float hv = (1.f - zz)*nn;
    h_all[(((size_t)s*BB + b)*3 + l)*HH + h] = hv;
    if (writeHT) hT_out[((size_t)s*HH + h)*BB + b] = hv;
  }
}

// ---------- dots: one wave per (s,b,l) row ----------
__global__ __launch_bounds__(256) void dots2(const float* __restrict__ h_all,
                                             const double* __restrict__ w_d,
                                             const float* __restrict__ Ws,
                                             double* __restrict__ score_d,
                                             double* __restrict__ dmat_d){
  int row = blockIdx.x*4 + (threadIdx.x >> 6);     // [0, 576)
  int lane = threadIdx.x & 63;
  const float* hp = h_all + (size_t)row*HH;
  double a0=0.0, a1=0.0, a2=0.0, a3=0.0;
  #pragma unroll
  for (int jj = 0; jj < 8; ++jj){
    int h = jj*64 + lane;
    double hv = (double)hp[h];
    a0 += hv * w_d[h];
    a1 += hv * (double)Ws[h];
    a2 += hv * (double)Ws[768 + h];
    a3 += hv * (double)Ws[1536 + h];
  }
  for (int m = 32; m; m >>= 1){
    a0 += dshfl_xor(a0,m); a1 += dshfl_xor(a1,m);
    a2 += dshfl_xor(a2,m); a3 += dshfl_xor(a3,m);
  }
  if (lane == 0){
    score_d[row] = a0;
    dmat_d[row*3+0] = a1; dmat_d[row*3+1] = a2; dmat_d[row*3+2] = a3;
  }
}

// ---------- fused fold + xdot + softmax-sums: block t, 192 threads ----------
// Lint[t][cur*3+c] = (round(log2(sum_b softmax_c(P1[cur]+D[t])[b]) * 2^20) & ~3) | (2-c)
__global__ __launch_bounds__(192) void sums_x(const float* __restrict__ x,
                                              const float* __restrict__ Ws,
                                              const double* __restrict__ score_d,
                                              const double* __restrict__ dmat_d,
                                              const float* __restrict__ bs,
                                              int* __restrict__ Lint){
  __shared__ float xl[64*257];
  __shared__ float wsl[3*256];
  __shared__ double dl[3*64];
  __shared__ double P1L[576];
  int t = blockIdx.x, tid = threadIdx.x;
  int lane = tid & 63, w = tid >> 6;               // w = s (fold) / c (dot) / cur (final)
  for (int i = tid; i < 768; i += 192) wsl[i] = Ws[(i >> 8)*768 + 512 + (i & 255)];
  for (int q = tid; q < 4096; q += 192){           // stage x[:,t,:] via float4
    int r = q >> 6, i4 = q & 63;
    float4 v = *(const float4*)(x + ((size_t)r*TT + t)*IW + i4*4);
    float* dst = &xl[r*257 + i4*4];
    dst[0]=v.x; dst[1]=v.y; dst[2]=v.z; dst[3]=v.w;
  }
  {  // fold (redundant per block, cheap): P1L[s][c][b]
    int base = w*192 + lane*3;
    double s0 = score_d[base], s1 = score_d[base+1], s2 = score_d[base+2];
    double m = fmax(s0, fmax(s1, s2));
    double e0 = exp(s0-m), e1 = exp(s1-m), e2 = exp(s2-m);
    double inv = 1.0/(e0+e1+e2);
    e0 *= inv; e1 *= inv; e2 *= inv;
    for (int c = 0; c < 3; ++c){
      double v = e0*dmat_d[base*3 + c] + e1*dmat_d[(base+1)*3 + c] + e2*dmat_d[(base+2)*3 + c];
      P1L[(w*3 + c)*64 + lane] = v + (double)bs[c];
    }
  }
  __syncthreads();
  {
    const float* xr = &xl[lane*257];
    const float* wr = &wsl[w*256];
    double acc = 0.0;
    #pragma unroll 8
    for (int i = 0; i < 256; ++i) acc += (double)xr[i] * (double)wr[i];
    dl[w*64 + lane] = acc;
  }
  __syncthreads();
  double l0 = P1L[(w*3+0)*64 + lane] + dl[0*64 + lane];
  double l1 = P1L[(w*3+1)*64 + lane] + dl[1*64 + lane];
  double l2 = P1L[(w*3+2)*64 + lane] + dl[2*64 + lane];
  double m = fmax(l0, fmax(l1, l2));
  double e0 = exp(l0-m), e1 = exp(l1-m), e2 = exp(l2-m);
  double inv = 1.0/(e0+e1+e2);
  e0 *= inv; e1 *= inv; e2 *= inv;
  for (int mm = 32; mm; mm >>= 1){
    e0 += dshfl_xor(e0, mm); e1 += dshfl_xor(e1, mm); e2 += dshfl_xor(e2, mm);
  }
  if (lane == 0){
    int q0 = (int)lrintf(fmaxf(log2f((float)e0), -1500.f) * 1048576.0f);
    int q1 = (int)lrintf(fmaxf(log2f((float)e1), -1500.f) * 1048576.0f);
    int q2 = (int)lrintf(fmaxf(log2f((float)e2), -1500.f) * 1048576.0f);
    int* p = Lint + (size_t)t*12 + w*3;
    p[0] = (q0 & ~3) | 2;     // embed idx = 2-c so exact ties pick smallest c
    p[1] = (q1 & ~3) | 1;
    p[2] = (q2 & ~3) | 0;
  }
}

// ---------- VALU scan: no renorm (argmax-invariant), max3 + embedded index ----------
#define LOADI(X0,X1,X2, tt) do { int _t = (tt); if (_t > 511) _t = 511;  \
  const int4* _p = (const int4*)&lds[_t*12]; X0=_p[0]; X1=_p[1]; X2=_p[2]; } while(0)

#define STEPI(S0,S1,S2, kk) do {                                \
  int L0 = (cur==0)?S0.x:((cur==1)?S0.w:S1.z);                  \
  int L1 = (cur==0)?S0.y:((cur==1)?S1.x:S1.w);                  \
  int L2 = (cur==0)?S0.z:((cur==1)?S1.y:S2.x);                  \
  int v0 = L0-a0, v1 = L1-a1, v2 = L2-a2;                       \
  int bm = v0 > v1 ? v0 : v1; bm = bm > v2 ? bm : v2;           \
  int idx = bm & 3;                                             \
  cur = 2 - idx;                                                \
  a0 += (idx==2) ? PEN1 : 0;                                    \
  a1 += (idx==1) ? PEN1 : 0;                                    \
  a2 += (idx==0) ? PEN1 : 0;                                    \
  word |= (unsigned)cur << (2*(kk)); } while(0)

__global__ __launch_bounds__(64) void scan6(const int* __restrict__ Lint,
                                            unsigned* __restrict__ curpack){
  __shared__ int lds[TT*12];
  int lane = threadIdx.x;
  for (int i = lane*4; i < TT*12; i += 256)
    *(int4*)&lds[i] = *(const int4*)&Lint[i];
  __syncthreads();
  int a0 = PEN1, a1 = 0, a2 = 0, cur = 0;
  int4 A0,A1,A2,B0,B1,B2,C0,C1,C2,D0,D1,D2,E0,E1,E2,F0,F1,F2,G0,G1,G2,H0,H1,H2;
  LOADI(A0,A1,A2, 0); LOADI(B0,B1,B2, 1); LOADI(C0,C1,C2, 2); LOADI(D0,D1,D2, 3);
  LOADI(E0,E1,E2, 4); LOADI(F0,F1,F2, 5); LOADI(G0,G1,G2, 6); LOADI(H0,H1,H2, 7);
  for (int base = 0; base < 512; base += 16){
    unsigned word = 0u;
    if (base){ STEPI(A0,A1,A2, 0); }            // t=0: cur=0, bits stay 0
    LOADI(A0,A1,A2, base+8);
    STEPI(B0,B1,B2, 1);   LOADI(B0,B1,B2, base+9);
    STEPI(C0,C1,C2, 2);   LOADI(C0,C1,C2, base+10);
    STEPI(D0,D1,D2, 3);   LOADI(D0,D1,D2, base+11);
    STEPI(E0,E1,E2, 4);   LOADI(E0,E1,E2, base+12);
    STEPI(F0,F1,F2, 5);   LOADI(F0,F1,F2, base+13);
    STEPI(G0,G1,G2, 6);   LOADI(G0,G1,G2, base+14);
    STEPI(H0,H1,H2, 7);   LOADI(H0,H1,H2, base+15);
    STEPI(A0,A1,A2, 8);   LOADI(A0,A1,A2, base+16);
    STEPI(B0,B1,B2, 9);   LOADI(B0,B1,B2, base+17);
    STEPI(C0,C1,C2, 10);  LOADI(C0,C1,C2, base+18);
    STEPI(D0,D1,D2, 11);  LOADI(D0,D1,D2, base+19);
    STEPI(E0,E1,E2, 12);  LOADI(E0,E1,E2, base+20);
    STEPI(F0,F1,F2, 13);  LOADI(F0,F1,F2, base+21);
    STEPI(G0,G1,G2, 14);  LOADI(G0,G1,G2, base+22);
    STEPI(H0,H1,H2, 15);  LOADI(H0,H1,H2, base+23);
    if (lane == 0) curpack[base >> 4] = word;
  }
}

// ---------- outputs (f32), fused; cur from 2-bit packed words ----------
__global__ __launch_bounds__(256) void out_all(const float* __restrict__ h_all,
                                               const unsigned* __restrict__ curpack,
                                               float* __restrict__ out){
  int blk = blockIdx.x;
  if (blk < 512){
    int t = blk;
    int cur = (int)((curpack[t >> 4] >> ((t & 15)*2)) & 3u);
    const float* base = h_all + (size_t)cur*98304 + 2*HH;  // [cur][b][2][:], b-stride 1536
    int tid = threadIdx.x;
    for (int k = 0; k < 32; ++k){
      int e4 = (k*256 + tid)*4;                            // [0, 32768)
      int b = e4 >> 9, h = e4 & 511;
      float4 v = *(const float4*)(base + (size_t)b*1536 + h);
      *(float4*)(&out[((size_t)b*TT + t)*HH + h]) = v;
    }
  } else {
    int cur = (int)((curpack[31] >> 30) & 3u);
    int e4 = ((blk - 512)*256 + threadIdx.x)*4;            // [0, 98304)
    float4 v = *(const float4*)(h_all + (size_t)cur*98304 + e4);
    *(float4*)(&out[(size_t)BB*TT*HH + e4]) = v;
  }
}

extern "C" void kernel_launch(void* const* d_in, const int* in_sizes, int n_in,
                              void* d_out, int out_size, void* d_ws, size_t ws_size,
                              hipStream_t stream){
  const float* x    = (const float*)d_in[0];
  const float* Wl   = (const float*)d_in[1];
  // d_in[2] = bl : constant over L inside softmax -> cancels; unused
  const float* Ws   = (const float*)d_in[3];
  const float* bs   = (const float*)d_in[4];
  const float* Wih0 = (const float*)d_in[5];
  const float* bih0 = (const float*)d_in[6];
  const float* bhh0 = (const float*)d_in[7];
  const float* WihL = (const float*)d_in[8];
  const float* bihL = (const float*)d_in[9];
  const float* bhhL = (const float*)d_in[10];
  float* out = (float*)d_out;

  // ---- sentinels ----
  static const int exp_sizes[11] = {8388608, 262144, 512, 2304, 3,
                                    1179648, 4608, 4608, 4718592, 9216, 9216};
  int bad = 0;
  if (n_in != 11) bad = 13;
  else {
    for (int i = 0; i < 11; ++i) if (in_sizes[i] != exp_sizes[i]) { bad = i + 1; break; }
  }
  if (!bad && out_size != 16875520) bad = 12;
  if (bad){
    sentinel_k<<<dim3(1), dim3(1), 0, stream>>>(out, 1048576.0f * (float)bad);
    return;
  }
  if (ws_size < 1292416){
    sentinel_k<<<dim3(1), dim3(1), 0, stream>>>(out, 3.0e7f + (float)(ws_size >> 6));
    return;
  }

  // ---- ws layout (1,292,416 B) ----
  double*   w_d     = (double*)d_ws;              // 512 f64
  double*   score_d = w_d + 512;                  // 576 f64
  double*   dmat_d  = score_d + 576;              // 1728 f64
  int*      Lint    = (int*)(dmat_d + 1728);      // 6144 i32
  float*    h_all   = (float*)(Lint + 6144);      // 294912 f32
  float*    x0T     = h_all + 294912;             // 16384 f32
  unsigned* curpack = (unsigned*)(x0T + 16384);   // 32 u32

  // ---- hT double-buffer in d_out tail (dead before out_all writes) ----
  char* outb = (char*)d_out;
  float* hT0 = (float*)(outb + 50331648);         // [3][512][64] f32 = 393,216 B
  float* hT1 = hT0 + 98304;                       // same

  prep<<<dim3(72), dim3(256), 0, stream>>>(x, x0T, Wl, w_d);

  // fused GRU stack
  gru_fused<256><<<dim3(192), dim3(256), 0, stream>>>(
      Wih0, (long)G3H*IW, bih0, G3H, bhh0, G3H, x0T, 0, h_all, hT0, 1, 0);
  gru_fused<512><<<dim3(192), dim3(256), 0, stream>>>(
      WihL, (long)2*G3H*HH, bihL, 2*G3H, bhhL, 2*G3H, hT0, HH*BB, h_all, hT1, 1, 1);
  gru_fused<512><<<dim3(192), dim3(256), 0, stream>>>(
      WihL + (size_t)G3H*HH, (long)2*G3H*HH, bihL + G3H, 2*G3H, bhhL + G3H, 2*G3H,
      hT1, HH*BB, h_all, hT0, 0, 2);

  dots2 <<<dim3(144), dim3(256), 0, stream>>>(h_all, w_d, Ws, score_d, dmat_d);
  sums_x<<<dim3(512), dim3(192), 0, stream>>>(x, Ws, score_d, dmat_d, bs, Lint);

  scan6<<<dim3(1), dim3(64), 0, stream>>>(Lint, curpack);

  out_all<<<dim3(608), dim3(256), 0, stream>>>(h_all, curpack, out);
}

// Round 9
// 127.475 us; speedup vs baseline: 1.9546x; 1.5143x over previous
//
#include <hip/hip_runtime.h>
#include <hip/hip_bf16.h>
#include <math.h>

#define BB 64
#define TT 512
#define IW 256
#define HH 512
#define G3H 1536
#define PEN1 (1<<20)

__device__ __forceinline__ double dshfl_xor(double v, int m){
  int2 a = *(int2*)&v;
  a.x = __shfl_xor(a.x, m, 64);
  a.y = __shfl_xor(a.y, m, 64);
  return *(double*)&a;
}

__global__ void sentinel_k(float* out, float v){ out[0] = v; }

// ---------- prep: transpose x0 (blocks 0..63) + colsum Wl (blocks 64..71) ----------
__global__ __launch_bounds__(256) void prep(const float* __restrict__ x, float* __restrict__ x0T,
                                            const float* __restrict__ Wl, double* __restrict__ w_d){
  if (blockIdx.x < 64){
    int idx = blockIdx.x*256 + threadIdx.x;          // [0, 16384)
    int b = idx >> 8, i = idx & 255;
    x0T[i*64 + b] = x[(size_t)b*TT*IW + i];          // x[b][0][i]
  } else {
    __shared__ double part[4][64];
    int lane = threadIdx.x & 63, ty = threadIdx.x >> 6;
    int h = (blockIdx.x - 64)*64 + lane;
    double acc = 0.0;
    for (int j = ty*128; j < ty*128 + 128; ++j) acc += (double)Wl[(size_t)j*HH + h];
    part[ty][lane] = acc;
    __syncthreads();
    if (ty == 0) w_d[h] = part[0][lane] + part[1][lane] + part[2][lane] + part[3][lane];
  }
}

// ---------- K-split gates GEMM: partials gp[kc][r][b], r = s*G3H + g ----------
// block = (row-group of 16, k-chunk of KCH); 256 threads; W tile + in tile staged in LDS
template<int K, int KCH>
__global__ __launch_bounds__(256) void gates_part(const float* __restrict__ W, long wS,
                                                  const float* __restrict__ in, int inS,
                                                  float* __restrict__ gp){
  __shared__ float wl[16][KCH];
  __shared__ float il[KCH][64];
  const int KC4 = KCH/4;
  int tid = threadIdx.x;
  int rg = blockIdx.x % 288;
  int kc = blockIdx.x / 288;
  int r0 = rg*16;                       // [0, 4608)
  int s  = r0 / G3H;
  int g0 = r0 - s*G3H;
  int k0 = kc*KCH;
  const float* Wbase = W + (size_t)s*wS + (size_t)g0*K + k0;
  for (int q = tid; q < 16*KC4; q += 256){
    int r = q / KC4, i4 = q % KC4;
    *(float4*)&wl[r][i4*4] = *(const float4*)(Wbase + (size_t)r*K + i4*4);
  }
  const float* ibase = in + (size_t)s*inS + (size_t)k0*64;
  for (int q = tid; q < KCH*16; q += 256){
    int k = q >> 4, b4 = q & 15;
    *(float4*)&il[k][b4*4] = *(const float4*)(ibase + k*64 + b4*4);
  }
  __syncthreads();
  int lane = tid & 63, wv = tid >> 6;
  int j = wv*4;
  const float4* w0 = (const float4*)wl[j];
  const float4* w1 = (const float4*)wl[j+1];
  const float4* w2 = (const float4*)wl[j+2];
  const float4* w3 = (const float4*)wl[j+3];
  float a0=0.f, a1=0.f, a2=0.f, a3=0.f;
  #pragma unroll 8
  for (int k4 = 0; k4 < KC4; ++k4){
    float x0 = il[k4*4+0][lane];
    float x1 = il[k4*4+1][lane];
    float x2 = il[k4*4+2][lane];
    float x3 = il[k4*4+3][lane];
    float4 wa = w0[k4], wb = w1[k4], wc = w2[k4], wd = w3[k4];
    a0 += wa.x*x0 + wa.y*x1 + wa.z*x2 + wa.w*x3;
    a1 += wb.x*x0 + wb.y*x1 + wb.z*x2 + wb.w*x3;
    a2 += wc.x*x0 + wc.y*x1 + wc.z*x2 + wc.w*x3;
    a3 += wd.x*x0 + wd.y*x1 + wd.z*x2 + wd.w*x3;
  }
  float* op = gp + ((size_t)kc*4608 + r0 + j)*64 + lane;
  op[0] = a0; op[64] = a1; op[128] = a2; op[192] = a3;
}

// ---------- partial-reduce + GRU activation ----------
template<int NKC>
__global__ __launch_bounds__(256) void gru_act(const float* __restrict__ gp,
                                               const float* __restrict__ bih, long bihS,
                                               const float* __restrict__ bhh, long bhhS,
                                               float* __restrict__ h_all,
                                               float* __restrict__ hT_out, int writeHT, int l){
  int idx = blockIdx.x*256 + threadIdx.x;          // [0, 98304)
  int b = idx & 63;
  int h = (idx >> 6) & 511;
  int s = idx >> 15;
  size_t r = (size_t)s*G3H;
  float gr=0.f, gz=0.f, gn=0.f;
  #pragma unroll
  for (int kc = 0; kc < NKC; ++kc){
    const float* p = gp + (size_t)kc*294912;
    gr += p[(r + h)*64 + b];
    gz += p[(r + 512 + h)*64 + b];
    gn += p[(r + 1024 + h)*64 + b];
  }
  const float* bi = bih + (size_t)s*bihS;
  const float* bh = bhh + (size_t)s*bhhS;
  float rr = 1.f/(1.f + expf(-(gr + bi[h] + bh[h])));
  float zz = 1.f/(1.f + expf(-(gz + bi[512+h] + bh[512+h])));
  float nn = tanhf(gn + bi[1024+h] + rr*bh[1024+h]);
  float hv = (1.f - zz)*nn;
  h_all[(((size_t)s*BB + b)*3 + l)*HH + h] = hv;
  if (writeHT) hT_out[((size_t)s*HH + h)*BB + b] = hv;
}

// ---------- dots: one wave per (s,b,l) row ----------
__global__ __launch_bounds__(256) void dots2(const float* __restrict__ h_all,
                                             const double* __restrict__ w_d,
                                             const float* __restrict__ Ws,
                                             double* __restrict__ score_d,
                                             double* __restrict__ dmat_d){
  int row = blockIdx.x*4 + (threadIdx.x >> 6);     // [0, 576)
  int lane = threadIdx.x & 63;
  const float* hp = h_all + (size_t)row*HH;
  double a0=0.0, a1=0.0, a2=0.0, a3=0.0;
  #pragma unroll
  for (int jj = 0; jj < 8; ++jj){
    int h = jj*64 + lane;
    double hv = (double)hp[h];
    a0 += hv * w_d[h];
    a1 += hv * (double)Ws[h];
    a2 += hv * (double)Ws[768 + h];
    a3 += hv * (double)Ws[1536 + h];
  }
  for (int m = 32; m; m >>= 1){
    a0 += dshfl_xor(a0,m); a1 += dshfl_xor(a1,m);
    a2 += dshfl_xor(a2,m); a3 += dshfl_xor(a3,m);
  }
  if (lane == 0){
    score_d[row] = a0;
    dmat_d[row*3+0] = a1; dmat_d[row*3+1] = a2; dmat_d[row*3+2] = a3;
  }
}

// ---------- fused fold + xdot + softmax-sums: block t, 192 threads ----------
// Lint[t][cur*3+c] = (round(log2(sum_b softmax_c(P1[cur]+D[t])[b]) * 2^20) & ~3) | (2-c)
__global__ __launch_bounds__(192) void sums_x(const float* __restrict__ x,
                                              const float* __restrict__ Ws,
                                              const double* __restrict__ score_d,
                                              const double* __restrict__ dmat_d,
                                              const float* __restrict__ bs,
                                              int* __restrict__ Lint){
  __shared__ float xl[64*257];
  __shared__ float wsl[3*256];
  __shared__ double dl[3*64];
  __shared__ double P1L[576];
  int t = blockIdx.x, tid = threadIdx.x;
  int lane = tid & 63, w = tid >> 6;               // w = s (fold) / c (dot) / cur (final)
  for (int i = tid; i < 768; i += 192) wsl[i] = Ws[(i >> 8)*768 + 512 + (i & 255)];
  for (int q = tid; q < 4096; q += 192){           // stage x[:,t,:] via float4
    int r = q >> 6, i4 = q & 63;
    float4 v = *(const float4*)(x + ((size_t)r*TT + t)*IW + i4*4);
    float* dst = &xl[r*257 + i4*4];
    dst[0]=v.x; dst[1]=v.y; dst[2]=v.z; dst[3]=v.w;
  }
  {  // fold (redundant per block, cheap): P1L[s][c][b]
    int base = w*192 + lane*3;
    double s0 = score_d[base], s1 = score_d[base+1], s2 = score_d[base+2];
    double m = fmax(s0, fmax(s1, s2));
    double e0 = exp(s0-m), e1 = exp(s1-m), e2 = exp(s2-m);
    double inv = 1.0/(e0+e1+e2);
    e0 *= inv; e1 *= inv; e2 *= inv;
    for (int c = 0; c < 3; ++c){
      double v = e0*dmat_d[base*3 + c] + e1*dmat_d[(base+1)*3 + c] + e2*dmat_d[(base+2)*3 + c];
      P1L[(w*3 + c)*64 + lane] = v + (double)bs[c];
    }
  }
  __syncthreads();
  {
    const float* xr = &xl[lane*257];
    const float* wr = &wsl[w*256];
    double acc = 0.0;
    #pragma unroll 8
    for (int i = 0; i < 256; ++i) acc += (double)xr[i] * (double)wr[i];
    dl[w*64 + lane] = acc;
  }
  __syncthreads();
  double l0 = P1L[(w*3+0)*64 + lane] + dl[0*64 + lane];
  double l1 = P1L[(w*3+1)*64 + lane] + dl[1*64 + lane];
  double l2 = P1L[(w*3+2)*64 + lane] + dl[2*64 + lane];
  double m = fmax(l0, fmax(l1, l2));
  double e0 = exp(l0-m), e1 = exp(l1-m), e2 = exp(l2-m);
  double inv = 1.0/(e0+e1+e2);
  e0 *= inv; e1 *= inv; e2 *= inv;
  for (int mm = 32; mm; mm >>= 1){
    e0 += dshfl_xor(e0, mm); e1 += dshfl_xor(e1, mm); e2 += dshfl_xor(e2, mm);
  }
  if (lane == 0){
    int q0 = (int)lrintf(fmaxf(log2f((float)e0), -1500.f) * 1048576.0f);
    int q1 = (int)lrintf(fmaxf(log2f((float)e1), -1500.f) * 1048576.0f);
    int q2 = (int)lrintf(fmaxf(log2f((float)e2), -1500.f) * 1048576.0f);
    int* p = Lint + (size_t)t*12 + w*3;
    p[0] = (q0 & ~3) | 2;     // embed idx = 2-c so exact ties pick smallest c
    p[1] = (q1 & ~3) | 1;
    p[2] = (q2 & ~3) | 0;
  }
}

// ---------- VALU scan: no renorm (argmax-invariant), max3 + embedded index ----------
#define LOADI(X0,X1,X2, tt) do { int _t = (tt); if (_t > 511) _t = 511;  \
  const int4* _p = (const int4*)&lds[_t*12]; X0=_p[0]; X1=_p[1]; X2=_p[2]; } while(0)

#define STEPI(S0,S1,S2, kk) do {                                \
  int L0 = (cur==0)?S0.x:((cur==1)?S0.w:S1.z);                  \
  int L1 = (cur==0)?S0.y:((cur==1)?S1.x:S1.w);                  \
  int L2 = (cur==0)?S0.z:((cur==1)?S1.y:S2.x);                  \
  int v0 = L0-a0, v1 = L1-a1, v2 = L2-a2;                       \
  int bm = v0 > v1 ? v0 : v1; bm = bm > v2 ? bm : v2;           \
  int idx = bm & 3;                                             \
  cur = 2 - idx;                                                \
  a0 += (idx==2) ? PEN1 : 0;                                    \
  a1 += (idx==1) ? PEN1 : 0;                                    \
  a2 += (idx==0) ? PEN1 : 0;                                    \
  word |= (unsigned)cur << (2*(kk)); } while(0)

__global__ __launch_bounds__(64) void scan6(const int* __restrict__ Lint,
                                            unsigned* __restrict__ curpack){
  __shared__ int lds[TT*12];
  int lane = threadIdx.x;
  for (int i = lane*4; i < TT*12; i += 256)
    *(int4*)&lds[i] = *(const int4*)&Lint[i];
  __syncthreads();
  int a0 = PEN1, a1 = 0, a2 = 0, cur = 0;
  int4 A0,A1,A2,B0,B1,B2,C0,C1,C2,D0,D1,D2,E0,E1,E2,F0,F1,F2,G0,G1,G2,H0,H1,H2;
  LOADI(A0,A1,A2, 0); LOADI(B0,B1,B2, 1); LOADI(C0,C1,C2, 2); LOADI(D0,D1,D2, 3);
  LOADI(E0,E1,E2, 4); LOADI(F0,F1,F2, 5); LOADI(G0,G1,G2, 6); LOADI(H0,H1,H2, 7);
  for (int base = 0; base < 512; base += 16){
    unsigned word = 0u;
    if (base){ STEPI(A0,A1,A2, 0); }            // t=0: cur=0, bits stay 0
    LOADI(A0,A1,A2, base+8);
    STEPI(B0,B1,B2, 1);   LOADI(B0,B1,B2, base+9);
    STEPI(C0,C1,C2, 2);   LOADI(C0,C1,C2, base+10);
    STEPI(D0,D1,D2, 3);   LOADI(D0,D1,D2, base+11);
    STEPI(E0,E1,E2, 4);   LOADI(E0,E1,E2, base+12);
    STEPI(F0,F1,F2, 5);   LOADI(F0,F1,F2, base+13);
    STEPI(G0,G1,G2, 6);   LOADI(G0,G1,G2, base+14);
    STEPI(H0,H1,H2, 7);   LOADI(H0,H1,H2, base+15);
    STEPI(A0,A1,A2, 8);   LOADI(A0,A1,A2, base+16);
    STEPI(B0,B1,B2, 9);   LOADI(B0,B1,B2, base+17);
    STEPI(C0,C1,C2, 10);  LOADI(C0,C1,C2, base+18);
    STEPI(D0,D1,D2, 11);  LOADI(D0,D1,D2, base+19);
    STEPI(E0,E1,E2, 12);  LOADI(E0,E1,E2, base+20);
    STEPI(F0,F1,F2, 13);  LOADI(F0,F1,F2, base+21);
    STEPI(G0,G1,G2, 14);  LOADI(G0,G1,G2, base+22);
    STEPI(H0,H1,H2, 15);  LOADI(H0,H1,H2, base+23);
    if (lane == 0) curpack[base >> 4] = word;
  }
}

// ---------- outputs (f32), fused; cur from 2-bit packed words ----------
__global__ __launch_bounds__(256) void out_all(const float* __restrict__ h_all,
                                               const unsigned* __restrict__ curpack,
                                               float* __restrict__ out){
  int blk = blockIdx.x;
  if (blk < 512){
    int t = blk;
    int cur = (int)((curpack[t >> 4] >> ((t & 15)*2)) & 3u);
    const float* base = h_all + (size_t)cur*98304 + 2*HH;  // [cur][b][2][:], b-stride 1536
    int tid = threadIdx.x;
    for (int k = 0; k < 32; ++k){
      int e4 = (k*256 + tid)*4;                            // [0, 32768)
      int b = e4 >> 9, h = e4 & 511;
      float4 v = *(const float4*)(base + (size_t)b*1536 + h);
      *(float4*)(&out[((size_t)b*TT + t)*HH + h]) = v;
    }
  } else {
    int cur = (int)((curpack[31] >> 30) & 3u);
    int e4 = ((blk - 512)*256 + threadIdx.x)*4;            // [0, 98304)
    float4 v = *(const float4*)(h_all + (size_t)cur*98304 + e4);
    *(float4*)(&out[(size_t)BB*TT*HH + e4]) = v;
  }
}

extern "C" void kernel_launch(void* const* d_in, const int* in_sizes, int n_in,
                              void* d_out, int out_size, void* d_ws, size_t ws_size,
                              hipStream_t stream){
  const float* x    = (const float*)d_in[0];
  const float* Wl   = (const float*)d_in[1];
  // d_in[2] = bl : constant over L inside softmax -> cancels; unused
  const float* Ws   = (const float*)d_in[3];
  const float* bs   = (const float*)d_in[4];
  const float* Wih0 = (const float*)d_in[5];
  const float* bih0 = (const float*)d_in[6];
  const float* bhh0 = (const float*)d_in[7];
  const float* WihL = (const float*)d_in[8];
  const float* bihL = (const float*)d_in[9];
  const float* bhhL = (const float*)d_in[10];
  float* out = (float*)d_out;

  // ---- sentinels ----
  static const int exp_sizes[11] = {8388608, 262144, 512, 2304, 3,
                                    1179648, 4608, 4608, 4718592, 9216, 9216};
  int bad = 0;
  if (n_in != 11) bad = 13;
  else {
    for (int i = 0; i < 11; ++i) if (in_sizes[i] != exp_sizes[i]) { bad = i + 1; break; }
  }
  if (!bad && out_size != 16875520) bad = 12;
  if (bad){
    sentinel_k<<<dim3(1), dim3(1), 0, stream>>>(out, 1048576.0f * (float)bad);
    return;
  }
  if (ws_size < 1292416){
    sentinel_k<<<dim3(1), dim3(1), 0, stream>>>(out, 3.0e7f + (float)(ws_size >> 6));
    return;
  }

  // ---- ws layout (1,292,416 B) ----
  double*   w_d     = (double*)d_ws;              // 512 f64
  double*   score_d = w_d + 512;                  // 576 f64
  double*   dmat_d  = score_d + 576;              // 1728 f64
  int*      Lint    = (int*)(dmat_d + 1728);      // 6144 i32
  float*    h_all   = (float*)(Lint + 6144);      // 294912 f32
  float*    x0T     = h_all + 294912;             // 16384 f32
  unsigned* curpack = (unsigned*)(x0T + 16384);   // 32 u32

  // ---- big scratch in d_out tail (dead before out_all writes) ----
  char* outb = (char*)d_out;
  float* gip = (float*)(outb + 50331648);         // [4][4608][64] f32 = 4,718,592 B
  float* hT0 = gip + 1179648;                     // [3][512][64]  f32 =   393,216 B
  float* hT1 = hT0 + 98304;                       // same

  prep<<<dim3(72), dim3(256), 0, stream>>>(x, x0T, Wl, w_d);

  // GRU stack: K-split partial GEMM + activation
  gates_part<256,128><<<dim3(576),  dim3(256), 0, stream>>>(Wih0, (long)G3H*IW, x0T, 0, gip);
  gru_act<2>         <<<dim3(384),  dim3(256), 0, stream>>>(gip, bih0, G3H, bhh0, G3H, h_all, hT0, 1, 0);
  gates_part<512,128><<<dim3(1152), dim3(256), 0, stream>>>(WihL, (long)2*G3H*HH, hT0, HH*BB, gip);
  gru_act<4>         <<<dim3(384),  dim3(256), 0, stream>>>(gip, bihL, 2*G3H, bhhL, 2*G3H, h_all, hT1, 1, 1);
  gates_part<512,128><<<dim3(1152), dim3(256), 0, stream>>>(WihL + (size_t)G3H*HH, (long)2*G3H*HH, hT1, HH*BB, gip);
  gru_act<4>         <<<dim3(384),  dim3(256), 0, stream>>>(gip, bihL + G3H, 2*G3H, bhhL + G3H, 2*G3H, h_all, hT0, 0, 2);

  dots2 <<<dim3(144), dim3(256), 0, stream>>>(h_all, w_d, Ws, score_d, dmat_d);
  sums_x<<<dim3(512), dim3(192), 0, stream>>>(x, Ws, score_d, dmat_d, bs, Lint);

  scan6<<<dim3(1), dim3(64), 0, stream>>>(Lint, curpack);

  out_all<<<dim3(608), dim3(256), 0, stream>>>(h_all, curpack, out);
}

// Round 10
// 119.781 us; speedup vs baseline: 2.0802x; 1.0642x over previous
//
#include <hip/hip_runtime.h>
#include <hip/hip_bf16.h>
#include <math.h>

#define BB 64
#define TT 512
#define IW 256
#define HH 512
#define G3H 1536
#define PEN1 (1<<20)

__device__ __forceinline__ double dshfl_xor(double v, int m){
  int2 a = *(int2*)&v;
  a.x = __shfl_xor(a.x, m, 64);
  a.y = __shfl_xor(a.y, m, 64);
  return *(double*)&a;
}

__global__ void sentinel_k(float* out, float v){ out[0] = v; }

// ---------- prep: transpose x0 (blocks 0..63) + colsum Wl (blocks 64..71) ----------
__global__ __launch_bounds__(256) void prep(const float* __restrict__ x, float* __restrict__ x0T,
                                            const float* __restrict__ Wl, double* __restrict__ w_d){
  if (blockIdx.x < 64){
    int idx = blockIdx.x*256 + threadIdx.x;          // [0, 16384)
    int b = idx >> 8, i = idx & 255;
    x0T[i*64 + b] = x[(size_t)b*TT*IW + i];          // x[b][0][i]
  } else {
    __shared__ double part[4][64];
    int lane = threadIdx.x & 63, ty = threadIdx.x >> 6;
    int h = (blockIdx.x - 64)*64 + lane;
    double acc = 0.0;
    for (int j = ty*128; j < ty*128 + 128; ++j) acc += (double)Wl[(size_t)j*HH + h];
    part[ty][lane] = acc;
    __syncthreads();
    if (ty == 0) w_d[h] = part[0][lane] + part[1][lane] + part[2][lane] + part[3][lane];
  }
}

// ---------- K-split gates GEMM: W staged in LDS (broadcast reads), in from global ----------
// partials gp[kc][r][b], r = s*G3H + g; block = (16-row group, 128-k chunk); 256 threads
template<int K>
__global__ __launch_bounds__(256) void gates_part2(const float* __restrict__ W, long wS,
                                                   const float* __restrict__ in, int inS,
                                                   float* __restrict__ gp){
  __shared__ float wl[16][128];
  int tid = threadIdx.x;
  int rg = blockIdx.x % 288;
  int kc = blockIdx.x / 288;
  int r0 = rg*16;                       // [0, 4608)
  int s  = r0 / G3H;
  int g0 = r0 - s*G3H;
  int k0 = kc*128;
  const float* Wbase = W + (size_t)s*wS + (size_t)g0*K + k0;
  for (int q = tid; q < 16*32; q += 256){
    int r = q >> 5, i4 = q & 31;
    *(float4*)&wl[r][i4*4] = *(const float4*)(Wbase + (size_t)r*K + i4*4);
  }
  __syncthreads();
  int lane = tid & 63, wv = tid >> 6;
  int j = wv*4;
  const float4* w0 = (const float4*)wl[j];
  const float4* w1 = (const float4*)wl[j+1];
  const float4* w2 = (const float4*)wl[j+2];
  const float4* w3 = (const float4*)wl[j+3];
  const float* ip = in + (size_t)s*inS + (size_t)k0*64 + lane;
  float a0=0.f, a1=0.f, a2=0.f, a3=0.f;
  #pragma unroll 8
  for (int k4 = 0; k4 < 32; ++k4){
    float x0 = ip[(k4*4+0)*64];
    float x1 = ip[(k4*4+1)*64];
    float x2 = ip[(k4*4+2)*64];
    float x3 = ip[(k4*4+3)*64];
    float4 wa = w0[k4], wb = w1[k4], wc = w2[k4], wd = w3[k4];
    a0 += wa.x*x0 + wa.y*x1 + wa.z*x2 + wa.w*x3;
    a1 += wb.x*x0 + wb.y*x1 + wb.z*x2 + wb.w*x3;
    a2 += wc.x*x0 + wc.y*x1 + wc.z*x2 + wc.w*x3;
    a3 += wd.x*x0 + wd.y*x1 + wd.z*x2 + wd.w*x3;
  }
  float* op = gp + ((size_t)kc*4608 + r0 + j)*64 + lane;
  op[0] = a0; op[64] = a1; op[128] = a2; op[192] = a3;
}

// ---------- partial-reduce + GRU activation ----------
template<int NKC>
__global__ __launch_bounds__(256) void gru_act(const float* __restrict__ gp,
                                               const float* __restrict__ bih, long bihS,
                                               const float* __restrict__ bhh, long bhhS,
                                               float* __restrict__ h_all,
                                               float* __restrict__ hT_out, int writeHT, int l){
  int idx = blockIdx.x*256 + threadIdx.x;          // [0, 98304)
  int b = idx & 63;
  int h = (idx >> 6) & 511;
  int s = idx >> 15;
  size_t r = (size_t)s*G3H;
  float gr=0.f, gz=0.f, gn=0.f;
  #pragma unroll
  for (int kc = 0; kc < NKC; ++kc){
    const float* p = gp + (size_t)kc*294912;
    gr += p[(r + h)*64 + b];
    gz += p[(r + 512 + h)*64 + b];
    gn += p[(r + 1024 + h)*64 + b];
  }
  const float* bi = bih + (size_t)s*bihS;
  const float* bh = bhh + (size_t)s*bhhS;
  float rr = 1.f/(1.f + expf(-(gr + bi[h] + bh[h])));
  float zz = 1.f/(1.f + expf(-(gz + bi[512+h] + bh[512+h])));
  float nn = tanhf(gn + bi[1024+h] + rr*bh[1024+h]);
  float hv = (1.f - zz)*nn;
  h_all[(((size_t)s*BB + b)*3 + l)*HH + h] = hv;
  if (writeHT) hT_out[((size_t)s*HH + h)*BB + b] = hv;
}

// ---------- dots: one wave per (s,b,l) row ----------
__global__ __launch_bounds__(256) void dots2(const float* __restrict__ h_all,
                                             const double* __restrict__ w_d,
                                             const float* __restrict__ Ws,
                                             double* __restrict__ score_d,
                                             double* __restrict__ dmat_d){
  int row = blockIdx.x*4 + (threadIdx.x >> 6);     // [0, 576)
  int lane = threadIdx.x & 63;
  const float* hp = h_all + (size_t)row*HH;
  double a0=0.0, a1=0.0, a2=0.0, a3=0.0;
  #pragma unroll
  for (int jj = 0; jj < 8; ++jj){
    int h = jj*64 + lane;
    double hv = (double)hp[h];
    a0 += hv * w_d[h];
    a1 += hv * (double)Ws[h];
    a2 += hv * (double)Ws[768 + h];
    a3 += hv * (double)Ws[1536 + h];
  }
  for (int m = 32; m; m >>= 1){
    a0 += dshfl_xor(a0,m); a1 += dshfl_xor(a1,m);
    a2 += dshfl_xor(a2,m); a3 += dshfl_xor(a3,m);
  }
  if (lane == 0){
    score_d[row] = a0;
    dmat_d[row*3+0] = a1; dmat_d[row*3+1] = a2; dmat_d[row*3+2] = a3;
  }
}

// ---------- fused fold + xdot + softmax-sums: block t, 192 threads ----------
// Lint[t][cur*3+c] = (round(log2(sum_b softmax_c(P1[cur]+D[t])[b]) * 2^20) & ~3) | (2-c)
__global__ __launch_bounds__(192) void sums_x(const float* __restrict__ x,
                                              const float* __restrict__ Ws,
                                              const double* __restrict__ score_d,
                                              const double* __restrict__ dmat_d,
                                              const float* __restrict__ bs,
                                              int* __restrict__ Lint){
  __shared__ float xl[64*257];
  __shared__ float wsl[3*256];
  __shared__ double dl[3*64];
  __shared__ double P1L[576];
  int t = blockIdx.x, tid = threadIdx.x;
  int lane = tid & 63, w = tid >> 6;               // w = s (fold) / c (dot) / cur (final)
  for (int i = tid; i < 768; i += 192) wsl[i] = Ws[(i >> 8)*768 + 512 + (i & 255)];
  for (int q = tid; q < 4096; q += 192){           // stage x[:,t,:] via float4
    int r = q >> 6, i4 = q & 63;
    float4 v = *(const float4*)(x + ((size_t)r*TT + t)*IW + i4*4);
    float* dst = &xl[r*257 + i4*4];
    dst[0]=v.x; dst[1]=v.y; dst[2]=v.z; dst[3]=v.w;
  }
  {  // fold (redundant per block, cheap): P1L[s][c][b]
    int base = w*192 + lane*3;
    double s0 = score_d[base], s1 = score_d[base+1], s2 = score_d[base+2];
    double m = fmax(s0, fmax(s1, s2));
    double e0 = exp(s0-m), e1 = exp(s1-m), e2 = exp(s2-m);
    double inv = 1.0/(e0+e1+e2);
    e0 *= inv; e1 *= inv; e2 *= inv;
    for (int c = 0; c < 3; ++c){
      double v = e0*dmat_d[base*3 + c] + e1*dmat_d[(base+1)*3 + c] + e2*dmat_d[(base+2)*3 + c];
      P1L[(w*3 + c)*64 + lane] = v + (double)bs[c];
    }
  }
  __syncthreads();
  {
    const float* xr = &xl[lane*257];
    const float* wr = &wsl[w*256];
    double acc = 0.0;
    #pragma unroll 8
    for (int i = 0; i < 256; ++i) acc += (double)xr[i] * (double)wr[i];
    dl[w*64 + lane] = acc;
  }
  __syncthreads();
  double l0 = P1L[(w*3+0)*64 + lane] + dl[0*64 + lane];
  double l1 = P1L[(w*3+1)*64 + lane] + dl[1*64 + lane];
  double l2 = P1L[(w*3+2)*64 + lane] + dl[2*64 + lane];
  double m = fmax(l0, fmax(l1, l2));
  double e0 = exp(l0-m), e1 = exp(l1-m), e2 = exp(l2-m);
  double inv = 1.0/(e0+e1+e2);
  e0 *= inv; e1 *= inv; e2 *= inv;
  for (int mm = 32; mm; mm >>= 1){
    e0 += dshfl_xor(e0, mm); e1 += dshfl_xor(e1, mm); e2 += dshfl_xor(e2, mm);
  }
  if (lane == 0){
    int q0 = (int)lrintf(fmaxf(log2f((float)e0), -1500.f) * 1048576.0f);
    int q1 = (int)lrintf(fmaxf(log2f((float)e1), -1500.f) * 1048576.0f);
    int q2 = (int)lrintf(fmaxf(log2f((float)e2), -1500.f) * 1048576.0f);
    int* p = Lint + (size_t)t*12 + w*3;
    p[0] = (q0 & ~3) | 2;     // embed idx = 2-c so exact ties pick smallest c
    p[1] = (q1 & ~3) | 1;
    p[2] = (q2 & ~3) | 0;
  }
}

// ---------- VALU scan: no renorm (argmax-invariant), max3 + embedded index ----------
#define LOADI(X0,X1,X2, tt) do { int _t = (tt); if (_t > 511) _t = 511;  \
  const int4* _p = (const int4*)&lds[_t*12]; X0=_p[0]; X1=_p[1]; X2=_p[2]; } while(0)

#define STEPI(S0,S1,S2, kk) do {                                \
  int L0 = (cur==0)?S0.x:((cur==1)?S0.w:S1.z);                  \
  int L1 = (cur==0)?S0.y:((cur==1)?S1.x:S1.w);                  \
  int L2 = (cur==0)?S0.z:((cur==1)?S1.y:S2.x);                  \
  int v0 = L0-a0, v1 = L1-a1, v2 = L2-a2;                       \
  int bm = v0 > v1 ? v0 : v1; bm = bm > v2 ? bm : v2;           \
  int idx = bm & 3;                                             \
  cur = 2 - idx;                                                \
  a0 += (idx==2) ? PEN1 : 0;                                    \
  a1 += (idx==1) ? PEN1 : 0;                                    \
  a2 += (idx==0) ? PEN1 : 0;                                    \
  word |= (unsigned)cur << (2*(kk)); } while(0)

__global__ __launch_bounds__(64) void scan6(const int* __restrict__ Lint,
                                            unsigned* __restrict__ curpack){
  __shared__ int lds[TT*12];
  int lane = threadIdx.x;
  for (int i = lane*4; i < TT*12; i += 256)
    *(int4*)&lds[i] = *(const int4*)&Lint[i];
  __syncthreads();
  int a0 = PEN1, a1 = 0, a2 = 0, cur = 0;
  int4 A0,A1,A2,B0,B1,B2,C0,C1,C2,D0,D1,D2,E0,E1,E2,F0,F1,F2,G0,G1,G2,H0,H1,H2;
  LOADI(A0,A1,A2, 0); LOADI(B0,B1,B2, 1); LOADI(C0,C1,C2, 2); LOADI(D0,D1,D2, 3);
  LOADI(E0,E1,E2, 4); LOADI(F0,F1,F2, 5); LOADI(G0,G1,G2, 6); LOADI(H0,H1,H2, 7);
  for (int base = 0; base < 512; base += 16){
    unsigned word = 0u;
    if (base){ STEPI(A0,A1,A2, 0); }            // t=0: cur=0, bits stay 0
    LOADI(A0,A1,A2, base+8);
    STEPI(B0,B1,B2, 1);   LOADI(B0,B1,B2, base+9);
    STEPI(C0,C1,C2, 2);   LOADI(C0,C1,C2, base+10);
    STEPI(D0,D1,D2, 3);   LOADI(D0,D1,D2, base+11);
    STEPI(E0,E1,E2, 4);   LOADI(E0,E1,E2, base+12);
    STEPI(F0,F1,F2, 5);   LOADI(F0,F1,F2, base+13);
    STEPI(G0,G1,G2, 6);   LOADI(G0,G1,G2, base+14);
    STEPI(H0,H1,H2, 7);   LOADI(H0,H1,H2, base+15);
    STEPI(A0,A1,A2, 8);   LOADI(A0,A1,A2, base+16);
    STEPI(B0,B1,B2, 9);   LOADI(B0,B1,B2, base+17);
    STEPI(C0,C1,C2, 10);  LOADI(C0,C1,C2, base+18);
    STEPI(D0,D1,D2, 11);  LOADI(D0,D1,D2, base+19);
    STEPI(E0,E1,E2, 12);  LOADI(E0,E1,E2, base+20);
    STEPI(F0,F1,F2, 13);  LOADI(F0,F1,F2, base+21);
    STEPI(G0,G1,G2, 14);  LOADI(G0,G1,G2, base+22);
    STEPI(H0,H1,H2, 15);  LOADI(H0,H1,H2, base+23);
    if (lane == 0) curpack[base >> 4] = word;
  }
}

// ---------- outputs (f32), fused; cur from 2-bit packed words ----------
__global__ __launch_bounds__(256) void out_all(const float* __restrict__ h_all,
                                               const unsigned* __restrict__ curpack,
                                               float* __restrict__ out){
  int blk = blockIdx.x;
  if (blk < 512){
    int t = blk;
    int cur = (int)((curpack[t >> 4] >> ((t & 15)*2)) & 3u);
    const float* base = h_all + (size_t)cur*98304 + 2*HH;  // [cur][b][2][:], b-stride 1536
    int tid = threadIdx.x;
    for (int k = 0; k < 32; ++k){
      int e4 = (k*256 + tid)*4;                            // [0, 32768)
      int b = e4 >> 9, h = e4 & 511;
      float4 v = *(const float4*)(base + (size_t)b*1536 + h);
      *(float4*)(&out[((size_t)b*TT + t)*HH + h]) = v;
    }
  } else {
    int cur = (int)((curpack[31] >> 30) & 3u);
    int e4 = ((blk - 512)*256 + threadIdx.x)*4;            // [0, 98304)
    float4 v = *(const float4*)(h_all + (size_t)cur*98304 + e4);
    *(float4*)(&out[(size_t)BB*TT*HH + e4]) = v;
  }
}

extern "C" void kernel_launch(void* const* d_in, const int* in_sizes, int n_in,
                              void* d_out, int out_size, void* d_ws, size_t ws_size,
                              hipStream_t stream){
  const float* x    = (const float*)d_in[0];
  const float* Wl   = (const float*)d_in[1];
  // d_in[2] = bl : constant over L inside softmax -> cancels; unused
  const float* Ws   = (const float*)d_in[3];
  const float* bs   = (const float*)d_in[4];
  const float* Wih0 = (const float*)d_in[5];
  const float* bih0 = (const float*)d_in[6];
  const float* bhh0 = (const float*)d_in[7];
  const float* WihL = (const float*)d_in[8];
  const float* bihL = (const float*)d_in[9];
  const float* bhhL = (const float*)d_in[10];
  float* out = (float*)d_out;

  // ---- sentinels ----
  static const int exp_sizes[11] = {8388608, 262144, 512, 2304, 3,
                                    1179648, 4608, 4608, 4718592, 9216, 9216};
  int bad = 0;
  if (n_in != 11) bad = 13;
  else {
    for (int i = 0; i < 11; ++i) if (in_sizes[i] != exp_sizes[i]) { bad = i + 1; break; }
  }
  if (!bad && out_size != 16875520) bad = 12;
  if (bad){
    sentinel_k<<<dim3(1), dim3(1), 0, stream>>>(out, 1048576.0f * (float)bad);
    return;
  }
  if (ws_size < 1292416){
    sentinel_k<<<dim3(1), dim3(1), 0, stream>>>(out, 3.0e7f + (float)(ws_size >> 6));
    return;
  }

  // ---- ws layout (1,292,416 B) ----
  double*   w_d     = (double*)d_ws;              // 512 f64
  double*   score_d = w_d + 512;                  // 576 f64
  double*   dmat_d  = score_d + 576;              // 1728 f64
  int*      Lint    = (int*)(dmat_d + 1728);      // 6144 i32
  float*    h_all   = (float*)(Lint + 6144);      // 294912 f32
  float*    x0T     = h_all + 294912;             // 16384 f32
  unsigned* curpack = (unsigned*)(x0T + 16384);   // 32 u32

  // ---- big scratch in d_out tail (dead before out_all writes) ----
  char* outb = (char*)d_out;
  float* gip = (float*)(outb + 50331648);         // [4][4608][64] f32 = 4,718,592 B
  float* hT0 = gip + 1179648;                     // [3][512][64]  f32 =   393,216 B
  float* hT1 = hT0 + 98304;                       // same

  prep<<<dim3(72), dim3(256), 0, stream>>>(x, x0T, Wl, w_d);

  // GRU stack: K-split partial GEMM (W in LDS, in from global) + activation
  gates_part2<256><<<dim3(576),  dim3(256), 0, stream>>>(Wih0, (long)G3H*IW, x0T, 0, gip);
  gru_act<2>      <<<dim3(384),  dim3(256), 0, stream>>>(gip, bih0, G3H, bhh0, G3H, h_all, hT0, 1, 0);
  gates_part2<512><<<dim3(1152), dim3(256), 0, stream>>>(WihL, (long)2*G3H*HH, hT0, HH*BB, gip);
  gru_act<4>      <<<dim3(384),  dim3(256), 0, stream>>>(gip, bihL, 2*G3H, bhhL, 2*G3H, h_all, hT1, 1, 1);
  gates_part2<512><<<dim3(1152), dim3(256), 0, stream>>>(WihL + (size_t)G3H*HH, (long)2*G3H*HH, hT1, HH*BB, gip);
  gru_act<4>      <<<dim3(384),  dim3(256), 0, stream>>>(gip, bihL + G3H, 2*G3H, bhhL + G3H, 2*G3H, h_all, hT0, 0, 2);

  dots2 <<<dim3(144), dim3(256), 0, stream>>>(h_all, w_d, Ws, score_d, dmat_d);
  sums_x<<<dim3(512), dim3(192), 0, stream>>>(x, Ws, score_d, dmat_d, bs, Lint);

  scan6<<<dim3(1), dim3(64), 0, stream>>>(Lint, curpack);

  out_all<<<dim3(608), dim3(256), 0, stream>>>(h_all, curpack, out);
}

// Round 11
// 117.742 us; speedup vs baseline: 2.1162x; 1.0173x over previous
//
#include <hip/hip_runtime.h>
#include <hip/hip_bf16.h>
#include <math.h>

#define BB 64
#define TT 512
#define IW 256
#define HH 512
#define G3H 1536
#define PEN1 (1<<20)

__device__ __forceinline__ double dshfl_xor(double v, int m){
  int2 a = *(int2*)&v;
  a.x = __shfl_xor(a.x, m, 64);
  a.y = __shfl_xor(a.y, m, 64);
  return *(double*)&a;
}

__global__ void sentinel_k(float* out, float v){ out[0] = v; }

// ---------- layer-0 gates (stages x-slice in LDS, transposed) + colsum tail blocks ----------
// blocks 0..575: K-split gates for Wih0 (K=256, KCH=128); blocks 576..583: w_d = colsum(Wl)
__global__ __launch_bounds__(256) void gates0x(const float* __restrict__ x,
                                               const float* __restrict__ W,
                                               const float* __restrict__ Wl,
                                               double* __restrict__ w_d,
                                               float* __restrict__ gp){
  __shared__ float wl[16][128];
  __shared__ float il[128][65];
  __shared__ double part[4][64];
  int tid = threadIdx.x;
  int blk = blockIdx.x;
  if (blk >= 576){                                 // colsum Wl -> w_d
    int lane = tid & 63, ty = tid >> 6;
    int h = (blk - 576)*64 + lane;
    double acc = 0.0;
    for (int j = ty*128; j < ty*128 + 128; ++j) acc += (double)Wl[(size_t)j*HH + h];
    part[ty][lane] = acc;
    __syncthreads();
    if (ty == 0) w_d[h] = part[0][lane] + part[1][lane] + part[2][lane] + part[3][lane];
    return;
  }
  int rg = blk % 288, kc = blk / 288;
  int r0 = rg*16;                                  // [0, 4608)
  int s  = r0 / G3H;
  int g0 = r0 - s*G3H;
  int k0 = kc*128;
  const float* Wbase = W + (size_t)s*((size_t)G3H*IW) + (size_t)g0*IW + k0;
  for (int q = tid; q < 16*32; q += 256){
    int r = q >> 5, i4 = q & 31;
    *(float4*)&wl[r][i4*4] = *(const float4*)(Wbase + (size_t)r*IW + i4*4);
  }
  for (int q = tid; q < 64*32; q += 256){          // stage x[b][0][k0..k0+128) -> il[k][b]
    int row = q >> 5, f4 = q & 31;
    float4 v = *(const float4*)(x + (size_t)row*TT*IW + k0 + f4*4);
    il[f4*4+0][row] = v.x; il[f4*4+1][row] = v.y;
    il[f4*4+2][row] = v.z; il[f4*4+3][row] = v.w;
  }
  __syncthreads();
  int lane = tid & 63, wv = tid >> 6;
  int j = wv*4;
  const float4* w0 = (const float4*)wl[j];
  const float4* w1 = (const float4*)wl[j+1];
  const float4* w2 = (const float4*)wl[j+2];
  const float4* w3 = (const float4*)wl[j+3];
  float a0=0.f, a1=0.f, a2=0.f, a3=0.f;
  #pragma unroll 8
  for (int k4 = 0; k4 < 32; ++k4){
    float x0 = il[k4*4+0][lane];
    float x1 = il[k4*4+1][lane];
    float x2 = il[k4*4+2][lane];
    float x3 = il[k4*4+3][lane];
    float4 wa = w0[k4], wb = w1[k4], wc = w2[k4], wd = w3[k4];
    a0 += wa.x*x0 + wa.y*x1 + wa.z*x2 + wa.w*x3;
    a1 += wb.x*x0 + wb.y*x1 + wb.z*x2 + wb.w*x3;
    a2 += wc.x*x0 + wc.y*x1 + wc.z*x2 + wc.w*x3;
    a3 += wd.x*x0 + wd.y*x1 + wd.z*x2 + wd.w*x3;
  }
  float* op = gp + ((size_t)kc*4608 + r0 + j)*64 + lane;
  op[0] = a0; op[64] = a1; op[128] = a2; op[192] = a3;
}

// ---------- K-split gates GEMM (layers 1,2): W staged in LDS, in from global ----------
template<int K>
__global__ __launch_bounds__(256) void gates_part2(const float* __restrict__ W, long wS,
                                                   const float* __restrict__ in, int inS,
                                                   float* __restrict__ gp){
  __shared__ float wl[16][128];
  int tid = threadIdx.x;
  int rg = blockIdx.x % 288;
  int kc = blockIdx.x / 288;
  int r0 = rg*16;                       // [0, 4608)
  int s  = r0 / G3H;
  int g0 = r0 - s*G3H;
  int k0 = kc*128;
  const float* Wbase = W + (size_t)s*wS + (size_t)g0*K + k0;
  for (int q = tid; q < 16*32; q += 256){
    int r = q >> 5, i4 = q & 31;
    *(float4*)&wl[r][i4*4] = *(const float4*)(Wbase + (size_t)r*K + i4*4);
  }
  __syncthreads();
  int lane = tid & 63, wv = tid >> 6;
  int j = wv*4;
  const float4* w0 = (const float4*)wl[j];
  const float4* w1 = (const float4*)wl[j+1];
  const float4* w2 = (const float4*)wl[j+2];
  const float4* w3 = (const float4*)wl[j+3];
  const float* ip = in + (size_t)s*inS + (size_t)k0*64 + lane;
  float a0=0.f, a1=0.f, a2=0.f, a3=0.f;
  #pragma unroll 8
  for (int k4 = 0; k4 < 32; ++k4){
    float x0 = ip[(k4*4+0)*64];
    float x1 = ip[(k4*4+1)*64];
    float x2 = ip[(k4*4+2)*64];
    float x3 = ip[(k4*4+3)*64];
    float4 wa = w0[k4], wb = w1[k4], wc = w2[k4], wd = w3[k4];
    a0 += wa.x*x0 + wa.y*x1 + wa.z*x2 + wa.w*x3;
    a1 += wb.x*x0 + wb.y*x1 + wb.z*x2 + wb.w*x3;
    a2 += wc.x*x0 + wc.y*x1 + wc.z*x2 + wc.w*x3;
    a3 += wd.x*x0 + wd.y*x1 + wd.z*x2 + wd.w*x3;
  }
  float* op = gp + ((size_t)kc*4608 + r0 + j)*64 + lane;
  op[0] = a0; op[64] = a1; op[128] = a2; op[192] = a3;
}

// ---------- partial-reduce + GRU activation ----------
template<int NKC>
__global__ __launch_bounds__(256) void gru_act(const float* __restrict__ gp,
                                               const float* __restrict__ bih, long bihS,
                                               const float* __restrict__ bhh, long bhhS,
                                               float* __restrict__ h_all,
                                               float* __restrict__ hT_out, int writeHT, int l){
  int idx = blockIdx.x*256 + threadIdx.x;          // [0, 98304)
  int b = idx & 63;
  int h = (idx >> 6) & 511;
  int s = idx >> 15;
  size_t r = (size_t)s*G3H;
  float gr=0.f, gz=0.f, gn=0.f;
  #pragma unroll
  for (int kc = 0; kc < NKC; ++kc){
    const float* p = gp + (size_t)kc*294912;
    gr += p[(r + h)*64 + b];
    gz += p[(r + 512 + h)*64 + b];
    gn += p[(r + 1024 + h)*64 + b];
  }
  const float* bi = bih + (size_t)s*bihS;
  const float* bh = bhh + (size_t)s*bhhS;
  float rr = 1.f/(1.f + expf(-(gr + bi[h] + bh[h])));
  float zz = 1.f/(1.f + expf(-(gz + bi[512+h] + bh[512+h])));
  float nn = tanhf(gn + bi[1024+h] + rr*bh[1024+h]);
  float hv = (1.f - zz)*nn;
  h_all[(((size_t)s*BB + b)*3 + l)*HH + h] = hv;
  if (writeHT) hT_out[((size_t)s*HH + h)*BB + b] = hv;
}

// ---------- dots: one block per (s,b,l) row, 4-wave h-split ----------
__global__ __launch_bounds__(256) void dots2w(const float* __restrict__ h_all,
                                              const double* __restrict__ w_d,
                                              const float* __restrict__ Ws,
                                              double* __restrict__ score_d,
                                              double* __restrict__ dmat_d){
  __shared__ double red[4][4];
  int row = blockIdx.x;                            // [0, 576)
  int tid = threadIdx.x, lane = tid & 63, wv = tid >> 6;
  const float* hp = h_all + (size_t)row*HH;
  double a0=0.0, a1=0.0, a2=0.0, a3=0.0;
  #pragma unroll
  for (int jj = 0; jj < 2; ++jj){
    int h = wv*128 + jj*64 + lane;
    double hv = (double)hp[h];
    a0 += hv * w_d[h];
    a1 += hv * (double)Ws[h];
    a2 += hv * (double)Ws[768 + h];
    a3 += hv * (double)Ws[1536 + h];
  }
  for (int m = 32; m; m >>= 1){
    a0 += dshfl_xor(a0,m); a1 += dshfl_xor(a1,m);
    a2 += dshfl_xor(a2,m); a3 += dshfl_xor(a3,m);
  }
  if (lane == 0){ red[wv][0]=a0; red[wv][1]=a1; red[wv][2]=a2; red[wv][3]=a3; }
  __syncthreads();
  if (tid == 0){
    score_d[row]    = red[0][0]+red[1][0]+red[2][0]+red[3][0];
    dmat_d[row*3+0] = red[0][1]+red[1][1]+red[2][1]+red[3][1];
    dmat_d[row*3+1] = red[0][2]+red[1][2]+red[2][2]+red[3][2];
    dmat_d[row*3+2] = red[0][3]+red[1][3]+red[2][3]+red[3][3];
  }
}

// ---------- fused fold + xdot + softmax-sums: block t, 192 threads ----------
// Lint[t][cur*3+c] = (round(log2(sum_b softmax_c(P1[cur]+D[t])[b]) * 2^20) & ~3) | (2-c)
__global__ __launch_bounds__(192) void sums_x(const float* __restrict__ x,
                                              const float* __restrict__ Ws,
                                              const double* __restrict__ score_d,
                                              const double* __restrict__ dmat_d,
                                              const float* __restrict__ bs,
                                              int* __restrict__ Lint){
  __shared__ float xl[64*257];
  __shared__ float wsl[3*256];
  __shared__ double dl[3*64];
  __shared__ double P1L[576];
  int t = blockIdx.x, tid = threadIdx.x;
  int lane = tid & 63, w = tid >> 6;               // w = s (fold) / c (dot) / cur (final)
  for (int i = tid; i < 768; i += 192) wsl[i] = Ws[(i >> 8)*768 + 512 + (i & 255)];
  for (int q = tid; q < 4096; q += 192){           // stage x[:,t,:] via float4
    int r = q >> 6, i4 = q & 63;
    float4 v = *(const float4*)(x + ((size_t)r*TT + t)*IW + i4*4);
    float* dst = &xl[r*257 + i4*4];
    dst[0]=v.x; dst[1]=v.y; dst[2]=v.z; dst[3]=v.w;
  }
  {  // fold (redundant per block, cheap): P1L[s][c][b]
    int base = w*192 + lane*3;
    double s0 = score_d[base], s1 = score_d[base+1], s2 = score_d[base+2];
    double m = fmax(s0, fmax(s1, s2));
    double e0 = exp(s0-m), e1 = exp(s1-m), e2 = exp(s2-m);
    double inv = 1.0/(e0+e1+e2);
    e0 *= inv; e1 *= inv; e2 *= inv;
    for (int c = 0; c < 3; ++c){
      double v = e0*dmat_d[base*3 + c] + e1*dmat_d[(base+1)*3 + c] + e2*dmat_d[(base+2)*3 + c];
      P1L[(w*3 + c)*64 + lane] = v + (double)bs[c];
    }
  }
  __syncthreads();
  {
    const float* xr = &xl[lane*257];
    const float* wr = &wsl[w*256];
    double acc = 0.0;
    #pragma unroll 8
    for (int i = 0; i < 256; ++i) acc += (double)xr[i] * (double)wr[i];
    dl[w*64 + lane] = acc;
  }
  __syncthreads();
  double l0 = P1L[(w*3+0)*64 + lane] + dl[0*64 + lane];
  double l1 = P1L[(w*3+1)*64 + lane] + dl[1*64 + lane];
  double l2 = P1L[(w*3+2)*64 + lane] + dl[2*64 + lane];
  double m = fmax(l0, fmax(l1, l2));
  double e0 = exp(l0-m), e1 = exp(l1-m), e2 = exp(l2-m);
  double inv = 1.0/(e0+e1+e2);
  e0 *= inv; e1 *= inv; e2 *= inv;
  for (int mm = 32; mm; mm >>= 1){
    e0 += dshfl_xor(e0, mm); e1 += dshfl_xor(e1, mm); e2 += dshfl_xor(e2, mm);
  }
  if (lane == 0){
    int q0 = (int)lrintf(fmaxf(log2f((float)e0), -1500.f) * 1048576.0f);
    int q1 = (int)lrintf(fmaxf(log2f((float)e1), -1500.f) * 1048576.0f);
    int q2 = (int)lrintf(fmaxf(log2f((float)e2), -1500.f) * 1048576.0f);
    int* p = Lint + (size_t)t*12 + w*3;
    p[0] = (q0 & ~3) | 2;     // embed idx = 2-c so exact ties pick smallest c
    p[1] = (q1 & ~3) | 1;
    p[2] = (q2 & ~3) | 0;
  }
}

// ---------- VALU scan: no renorm (argmax-invariant), max3 + embedded index ----------
#define LOADI(X0,X1,X2, tt) do { int _t = (tt); if (_t > 511) _t = 511;  \
  const int4* _p = (const int4*)&lds[_t*12]; X0=_p[0]; X1=_p[1]; X2=_p[2]; } while(0)

#define STEPI(S0,S1,S2, kk) do {                                \
  int L0 = (cur==0)?S0.x:((cur==1)?S0.w:S1.z);                  \
  int L1 = (cur==0)?S0.y:((cur==1)?S1.x:S1.w);                  \
  int L2 = (cur==0)?S0.z:((cur==1)?S1.y:S2.x);                  \
  int v0 = L0-a0, v1 = L1-a1, v2 = L2-a2;                       \
  int bm = v0 > v1 ? v0 : v1; bm = bm > v2 ? bm : v2;           \
  int idx = bm & 3;                                             \
  cur = 2 - idx;                                                \
  a0 += (idx==2) ? PEN1 : 0;                                    \
  a1 += (idx==1) ? PEN1 : 0;                                    \
  a2 += (idx==0) ? PEN1 : 0;                                    \
  word |= (unsigned)cur << (2*(kk)); } while(0)

__global__ __launch_bounds__(64) void scan6(const int* __restrict__ Lint,
                                            unsigned* __restrict__ curpack){
  __shared__ int lds[TT*12];
  int lane = threadIdx.x;
  for (int i = lane*4; i < TT*12; i += 256)
    *(int4*)&lds[i] = *(const int4*)&Lint[i];
  __syncthreads();
  int a0 = PEN1, a1 = 0, a2 = 0, cur = 0;
  int4 A0,A1,A2,B0,B1,B2,C0,C1,C2,D0,D1,D2,E0,E1,E2,F0,F1,F2,G0,G1,G2,H0,H1,H2;
  LOADI(A0,A1,A2, 0); LOADI(B0,B1,B2, 1); LOADI(C0,C1,C2, 2); LOADI(D0,D1,D2, 3);
  LOADI(E0,E1,E2, 4); LOADI(F0,F1,F2, 5); LOADI(G0,G1,G2, 6); LOADI(H0,H1,H2, 7);
  for (int base = 0; base < 512; base += 16){
    unsigned word = 0u;
    if (base){ STEPI(A0,A1,A2, 0); }            // t=0: cur=0, bits stay 0
    LOADI(A0,A1,A2, base+8);
    STEPI(B0,B1,B2, 1);   LOADI(B0,B1,B2, base+9);
    STEPI(C0,C1,C2, 2);   LOADI(C0,C1,C2, base+10);
    STEPI(D0,D1,D2, 3);   LOADI(D0,D1,D2, base+11);
    STEPI(E0,E1,E2, 4);   LOADI(E0,E1,E2, base+12);
    STEPI(F0,F1,F2, 5);   LOADI(F0,F1,F2, base+13);
    STEPI(G0,G1,G2, 6);   LOADI(G0,G1,G2, base+14);
    STEPI(H0,H1,H2, 7);   LOADI(H0,H1,H2, base+15);
    STEPI(A0,A1,A2, 8);   LOADI(A0,A1,A2, base+16);
    STEPI(B0,B1,B2, 9);   LOADI(B0,B1,B2, base+17);
    STEPI(C0,C1,C2, 10);  LOADI(C0,C1,C2, base+18);
    STEPI(D0,D1,D2, 11);  LOADI(D0,D1,D2, base+19);
    STEPI(E0,E1,E2, 12);  LOADI(E0,E1,E2, base+20);
    STEPI(F0,F1,F2, 13);  LOADI(F0,F1,F2, base+21);
    STEPI(G0,G1,G2, 14);  LOADI(G0,G1,G2, base+22);
    STEPI(H0,H1,H2, 15);  LOADI(H0,H1,H2, base+23);
    if (lane == 0) curpack[base >> 4] = word;
  }
}

// ---------- outputs (f32), fused; cur from 2-bit packed words ----------
__global__ __launch_bounds__(256) void out_all(const float* __restrict__ h_all,
                                               const unsigned* __restrict__ curpack,
                                               float* __restrict__ out){
  int blk = blockIdx.x;
  if (blk < 512){
    int t = blk;
    int cur = (int)((curpack[t >> 4] >> ((t & 15)*2)) & 3u);
    const float* base = h_all + (size_t)cur*98304 + 2*HH;  // [cur][b][2][:], b-stride 1536
    int tid = threadIdx.x;
    for (int k = 0; k < 32; ++k){
      int e4 = (k*256 + tid)*4;                            // [0, 32768)
      int b = e4 >> 9, h = e4 & 511;
      float4 v = *(const float4*)(base + (size_t)b*1536 + h);
      *(float4*)(&out[((size_t)b*TT + t)*HH + h]) = v;
    }
  } else {
    int cur = (int)((curpack[31] >> 30) & 3u);
    int e4 = ((blk - 512)*256 + threadIdx.x)*4;            // [0, 98304)
    float4 v = *(const float4*)(h_all + (size_t)cur*98304 + e4);
    *(float4*)(&out[(size_t)BB*TT*HH + e4]) = v;
  }
}

extern "C" void kernel_launch(void* const* d_in, const int* in_sizes, int n_in,
                              void* d_out, int out_size, void* d_ws, size_t ws_size,
                              hipStream_t stream){
  const float* x    = (const float*)d_in[0];
  const float* Wl   = (const float*)d_in[1];
  // d_in[2] = bl : constant over L inside softmax -> cancels; unused
  const float* Ws   = (const float*)d_in[3];
  const float* bs   = (const float*)d_in[4];
  const float* Wih0 = (const float*)d_in[5];
  const float* bih0 = (const float*)d_in[6];
  const float* bhh0 = (const float*)d_in[7];
  const float* WihL = (const float*)d_in[8];
  const float* bihL = (const float*)d_in[9];
  const float* bhhL = (const float*)d_in[10];
  float* out = (float*)d_out;

  // ---- sentinels ----
  static const int exp_sizes[11] = {8388608, 262144, 512, 2304, 3,
                                    1179648, 4608, 4608, 4718592, 9216, 9216};
  int bad = 0;
  if (n_in != 11) bad = 13;
  else {
    for (int i = 0; i < 11; ++i) if (in_sizes[i] != exp_sizes[i]) { bad = i + 1; break; }
  }
  if (!bad && out_size != 16875520) bad = 12;
  if (bad){
    sentinel_k<<<dim3(1), dim3(1), 0, stream>>>(out, 1048576.0f * (float)bad);
    return;
  }
  if (ws_size < 1292416){
    sentinel_k<<<dim3(1), dim3(1), 0, stream>>>(out, 3.0e7f + (float)(ws_size >> 6));
    return;
  }

  // ---- ws layout ----
  double*   w_d     = (double*)d_ws;              // 512 f64
  double*   score_d = w_d + 512;                  // 576 f64
  double*   dmat_d  = score_d + 576;              // 1728 f64
  int*      Lint    = (int*)(dmat_d + 1728);      // 6144 i32
  float*    h_all   = (float*)(Lint + 6144);      // 294912 f32
  float*    x0T     = h_all + 294912;             // 16384 f32 (unused hole, kept for layout stability)
  unsigned* curpack = (unsigned*)(x0T + 16384);   // 32 u32

  // ---- big scratch in d_out tail (dead before out_all writes) ----
  char* outb = (char*)d_out;
  float* gip = (float*)(outb + 50331648);         // [4][4608][64] f32 = 4,718,592 B
  float* hT0 = gip + 1179648;                     // [3][512][64]  f32 =   393,216 B
  float* hT1 = hT0 + 98304;                       // same

  // GRU stack: K-split partial GEMM + activation (layer 0 self-stages x, + colsum tail)
  gates0x         <<<dim3(584),  dim3(256), 0, stream>>>(x, Wih0, Wl, w_d, gip);
  gru_act<2>      <<<dim3(384),  dim3(256), 0, stream>>>(gip, bih0, G3H, bhh0, G3H, h_all, hT0, 1, 0);
  gates_part2<512><<<dim3(1152), dim3(256), 0, stream>>>(WihL, (long)2*G3H*HH, hT0, HH*BB, gip);
  gru_act<4>      <<<dim3(384),  dim3(256), 0, stream>>>(gip, bihL, 2*G3H, bhhL, 2*G3H, h_all, hT1, 1, 1);
  gates_part2<512><<<dim3(1152), dim3(256), 0, stream>>>(WihL + (size_t)G3H*HH, (long)2*G3H*HH, hT1, HH*BB, gip);
  gru_act<4>      <<<dim3(384),  dim3(256), 0, stream>>>(gip, bihL + G3H, 2*G3H, bhhL + G3H, 2*G3H, h_all, hT0, 0, 2);

  dots2w<<<dim3(576), dim3(256), 0, stream>>>(h_all, w_d, Ws, score_d, dmat_d);
  sums_x<<<dim3(512), dim3(192), 0, stream>>>(x, Ws, score_d, dmat_d, bs, Lint);

  scan6<<<dim3(1), dim3(64), 0, stream>>>(Lint, curpack);

  out_all<<<dim3(608), dim3(256), 0, stream>>>(h_all, curpack, out);
}

// Round 12
// 117.632 us; speedup vs baseline: 2.1182x; 1.0009x over previous
//
#include <hip/hip_runtime.h>
#include <hip/hip_bf16.h>
#include <math.h>

#define BB 64
#define TT 512
#define IW 256
#define HH 512
#define G3H 1536
#define PEN1 (1<<20)

__device__ __forceinline__ double dshfl_xor(double v, int m){
  int2 a = *(int2*)&v;
  a.x = __shfl_xor(a.x, m, 64);
  a.y = __shfl_xor(a.y, m, 64);
  return *(double*)&a;
}

__global__ void sentinel_k(float* out, float v){ out[0] = v; }

// ---------- layer-0 gates (stages x-slice in LDS, transposed) + colsum tail blocks ----------
__global__ __launch_bounds__(256) void gates0x(const float* __restrict__ x,
                                               const float* __restrict__ W,
                                               const float* __restrict__ Wl,
                                               double* __restrict__ w_d,
                                               float* __restrict__ gp){
  __shared__ float wl[16][128];
  __shared__ float il[128][65];
  __shared__ double part[4][64];
  int tid = threadIdx.x;
  int blk = blockIdx.x;
  if (blk >= 576){                                 // colsum Wl -> w_d
    int lane = tid & 63, ty = tid >> 6;
    int h = (blk - 576)*64 + lane;
    double acc = 0.0;
    for (int j = ty*128; j < ty*128 + 128; ++j) acc += (double)Wl[(size_t)j*HH + h];
    part[ty][lane] = acc;
    __syncthreads();
    if (ty == 0) w_d[h] = part[0][lane] + part[1][lane] + part[2][lane] + part[3][lane];
    return;
  }
  int rg = blk % 288, kc = blk / 288;
  int r0 = rg*16;                                  // [0, 4608)
  int s  = r0 / G3H;
  int g0 = r0 - s*G3H;
  int k0 = kc*128;
  const float* Wbase = W + (size_t)s*((size_t)G3H*IW) + (size_t)g0*IW + k0;
  for (int q = tid; q < 16*32; q += 256){
    int r = q >> 5, i4 = q & 31;
    *(float4*)&wl[r][i4*4] = *(const float4*)(Wbase + (size_t)r*IW + i4*4);
  }
  for (int q = tid; q < 64*32; q += 256){          // stage x[b][0][k0..k0+128) -> il[k][b]
    int row = q >> 5, f4 = q & 31;
    float4 v = *(const float4*)(x + (size_t)row*TT*IW + k0 + f4*4);
    il[f4*4+0][row] = v.x; il[f4*4+1][row] = v.y;
    il[f4*4+2][row] = v.z; il[f4*4+3][row] = v.w;
  }
  __syncthreads();
  int lane = tid & 63, wv = tid >> 6;
  int j = wv*4;
  const float4* w0 = (const float4*)wl[j];
  const float4* w1 = (const float4*)wl[j+1];
  const float4* w2 = (const float4*)wl[j+2];
  const float4* w3 = (const float4*)wl[j+3];
  float a0=0.f, a1=0.f, a2=0.f, a3=0.f;
  #pragma unroll 8
  for (int k4 = 0; k4 < 32; ++k4){
    float x0 = il[k4*4+0][lane];
    float x1 = il[k4*4+1][lane];
    float x2 = il[k4*4+2][lane];
    float x3 = il[k4*4+3][lane];
    float4 wa = w0[k4], wb = w1[k4], wc = w2[k4], wd = w3[k4];
    a0 += wa.x*x0 + wa.y*x1 + wa.z*x2 + wa.w*x3;
    a1 += wb.x*x0 + wb.y*x1 + wb.z*x2 + wb.w*x3;
    a2 += wc.x*x0 + wc.y*x1 + wc.z*x2 + wc.w*x3;
    a3 += wd.x*x0 + wd.y*x1 + wd.z*x2 + wd.w*x3;
  }
  float* op = gp + ((size_t)kc*4608 + r0 + j)*64 + lane;
  op[0] = a0; op[64] = a1; op[128] = a2; op[192] = a3;
}

// ---------- K-split gates GEMM (layers 1,2): W staged in LDS, in from global ----------
template<int K>
__global__ __launch_bounds__(256) void gates_part2(const float* __restrict__ W, long wS,
                                                   const float* __restrict__ in, int inS,
                                                   float* __restrict__ gp){
  __shared__ float wl[16][128];
  int tid = threadIdx.x;
  int rg = blockIdx.x % 288;
  int kc = blockIdx.x / 288;
  int r0 = rg*16;                       // [0, 4608)
  int s  = r0 / G3H;
  int g0 = r0 - s*G3H;
  int k0 = kc*128;
  const float* Wbase = W + (size_t)s*wS + (size_t)g0*K + k0;
  for (int q = tid; q < 16*32; q += 256){
    int r = q >> 5, i4 = q & 31;
    *(float4*)&wl[r][i4*4] = *(const float4*)(Wbase + (size_t)r*K + i4*4);
  }
  __syncthreads();
  int lane = tid & 63, wv = tid >> 6;
  int j = wv*4;
  const float4* w0 = (const float4*)wl[j];
  const float4* w1 = (const float4*)wl[j+1];
  const float4* w2 = (const float4*)wl[j+2];
  const float4* w3 = (const float4*)wl[j+3];
  const float* ip = in + (size_t)s*inS + (size_t)k0*64 + lane;
  float a0=0.f, a1=0.f, a2=0.f, a3=0.f;
  #pragma unroll 8
  for (int k4 = 0; k4 < 32; ++k4){
    float x0 = ip[(k4*4+0)*64];
    float x1 = ip[(k4*4+1)*64];
    float x2 = ip[(k4*4+2)*64];
    float x3 = ip[(k4*4+3)*64];
    float4 wa = w0[k4], wb = w1[k4], wc = w2[k4], wd = w3[k4];
    a0 += wa.x*x0 + wa.y*x1 + wa.z*x2 + wa.w*x3;
    a1 += wb.x*x0 + wb.y*x1 + wb.z*x2 + wb.w*x3;
    a2 += wc.x*x0 + wc.y*x1 + wc.z*x2 + wc.w*x3;
    a3 += wd.x*x0 + wd.y*x1 + wd.z*x2 + wd.w*x3;
  }
  float* op = gp + ((size_t)kc*4608 + r0 + j)*64 + lane;
  op[0] = a0; op[64] = a1; op[128] = a2; op[192] = a3;
}

// ---------- partial-reduce + GRU activation ----------
template<int NKC>
__global__ __launch_bounds__(256) void gru_act(const float* __restrict__ gp,
                                               const float* __restrict__ bih, long bihS,
                                               const float* __restrict__ bhh, long bhhS,
                                               float* __restrict__ h_all,
                                               float* __restrict__ hT_out, int writeHT, int l){
  int idx = blockIdx.x*256 + threadIdx.x;          // [0, 98304)
  int b = idx & 63;
  int h = (idx >> 6) & 511;
  int s = idx >> 15;
  size_t r = (size_t)s*G3H;
  float gr=0.f, gz=0.f, gn=0.f;
  #pragma unroll
  for (int kc = 0; kc < NKC; ++kc){
    const float* p = gp + (size_t)kc*294912;
    gr += p[(r + h)*64 + b];
    gz += p[(r + 512 + h)*64 + b];
    gn += p[(r + 1024 + h)*64 + b];
  }
  const float* bi = bih + (size_t)s*bihS;
  const float* bh = bhh + (size_t)s*bhhS;
  float rr = 1.f/(1.f + expf(-(gr + bi[h] + bh[h])));
  float zz = 1.f/(1.f + expf(-(gz + bi[512+h] + bh[512+h])));
  float nn = tanhf(gn + bi[1024+h] + rr*bh[1024+h]);
  float hv = (1.f - zz)*nn;
  h_all[(((size_t)s*BB + b)*3 + l)*HH + h] = hv;
  if (writeHT) hT_out[((size_t)s*HH + h)*BB + b] = hv;
}

// ---------- dots: one block per (s,b,l) row, 4-wave h-split ----------
__global__ __launch_bounds__(256) void dots2w(const float* __restrict__ h_all,
                                              const double* __restrict__ w_d,
                                              const float* __restrict__ Ws,
                                              double* __restrict__ score_d,
                                              double* __restrict__ dmat_d){
  __shared__ double red[4][4];
  int row = blockIdx.x;                            // [0, 576)
  int tid = threadIdx.x, lane = tid & 63, wv = tid >> 6;
  const float* hp = h_all + (size_t)row*HH;
  double a0=0.0, a1=0.0, a2=0.0, a3=0.0;
  #pragma unroll
  for (int jj = 0; jj < 2; ++jj){
    int h = wv*128 + jj*64 + lane;
    double hv = (double)hp[h];
    a0 += hv * w_d[h];
    a1 += hv * (double)Ws[h];
    a2 += hv * (double)Ws[768 + h];
    a3 += hv * (double)Ws[1536 + h];
  }
  for (int m = 32; m; m >>= 1){
    a0 += dshfl_xor(a0,m); a1 += dshfl_xor(a1,m);
    a2 += dshfl_xor(a2,m); a3 += dshfl_xor(a3,m);
  }
  if (lane == 0){ red[wv][0]=a0; red[wv][1]=a1; red[wv][2]=a2; red[wv][3]=a3; }
  __syncthreads();
  if (tid == 0){
    score_d[row]    = red[0][0]+red[1][0]+red[2][0]+red[3][0];
    dmat_d[row*3+0] = red[0][1]+red[1][1]+red[2][1]+red[3][1];
    dmat_d[row*3+1] = red[0][2]+red[1][2]+red[2][2]+red[3][2];
    dmat_d[row*3+2] = red[0][3]+red[1][3]+red[2][3]+red[3][3];
  }
}

// ---------- fused fold + xdot + softmax-sums: block t, 192 threads ----------
__global__ __launch_bounds__(192) void sums_x(const float* __restrict__ x,
                                              const float* __restrict__ Ws,
                                              const double* __restrict__ score_d,
                                              const double* __restrict__ dmat_d,
                                              const float* __restrict__ bs,
                                              int* __restrict__ Lint){
  __shared__ float xl[64*257];
  __shared__ float wsl[3*256];
  __shared__ double dl[3*64];
  __shared__ double P1L[576];
  int t = blockIdx.x, tid = threadIdx.x;
  int lane = tid & 63, w = tid >> 6;               // w = s (fold) / c (dot) / cur (final)
  for (int i = tid; i < 768; i += 192) wsl[i] = Ws[(i >> 8)*768 + 512 + (i & 255)];
  for (int q = tid; q < 4096; q += 192){           // stage x[:,t,:] via float4
    int r = q >> 6, i4 = q & 63;
    float4 v = *(const float4*)(x + ((size_t)r*TT + t)*IW + i4*4);
    float* dst = &xl[r*257 + i4*4];
    dst[0]=v.x; dst[1]=v.y; dst[2]=v.z; dst[3]=v.w;
  }
  {  // fold (redundant per block, cheap): P1L[s][c][b]
    int base = w*192 + lane*3;
    double s0 = score_d[base], s1 = score_d[base+1], s2 = score_d[base+2];
    double m = fmax(s0, fmax(s1, s2));
    double e0 = exp(s0-m), e1 = exp(s1-m), e2 = exp(s2-m);
    double inv = 1.0/(e0+e1+e2);
    e0 *= inv; e1 *= inv; e2 *= inv;
    for (int c = 0; c < 3; ++c){
      double v = e0*dmat_d[base*3 + c] + e1*dmat_d[(base+1)*3 + c] + e2*dmat_d[(base+2)*3 + c];
      P1L[(w*3 + c)*64 + lane] = v + (double)bs[c];
    }
  }
  __syncthreads();
  {
    const float* xr = &xl[lane*257];
    const float* wr = &wsl[w*256];
    double acc = 0.0;
    #pragma unroll 8
    for (int i = 0; i < 256; ++i) acc += (double)xr[i] * (double)wr[i];
    dl[w*64 + lane] = acc;
  }
  __syncthreads();
  double l0 = P1L[(w*3+0)*64 + lane] + dl[0*64 + lane];
  double l1 = P1L[(w*3+1)*64 + lane] + dl[1*64 + lane];
  double l2 = P1L[(w*3+2)*64 + lane] + dl[2*64 + lane];
  double m = fmax(l0, fmax(l1, l2));
  double e0 = exp(l0-m), e1 = exp(l1-m), e2 = exp(l2-m);
  double inv = 1.0/(e0+e1+e2);
  e0 *= inv; e1 *= inv; e2 *= inv;
  for (int mm = 32; mm; mm >>= 1){
    e0 += dshfl_xor(e0, mm); e1 += dshfl_xor(e1, mm); e2 += dshfl_xor(e2, mm);
  }
  if (lane == 0){
    int q0 = (int)lrintf(fmaxf(log2f((float)e0), -1500.f) * 1048576.0f);
    int q1 = (int)lrintf(fmaxf(log2f((float)e1), -1500.f) * 1048576.0f);
    int q2 = (int)lrintf(fmaxf(log2f((float)e2), -1500.f) * 1048576.0f);
    int* p = Lint + (size_t)t*12 + w*3;
    p[0] = (q0 & ~3) | 2;     // embed idx = 2-c so exact ties pick smallest c
    p[1] = (q1 & ~3) | 1;
    p[2] = (q2 & ~3) | 0;
  }
}

// ---------- VALU scan: idx-based state (one op shorter chain), full-VGPR pipeline ----------
#define LOADI(X0,X1,X2, tt) do { int _t = (tt); if (_t > 511) _t = 511;  \
  const int4* _p = (const int4*)&lds[_t*12]; X0=_p[0]; X1=_p[1]; X2=_p[2]; } while(0)

// state: idx = 2-cur  (init cur=0 -> idx=2). Row select: idx==2 -> row0, idx==1 -> row1, else row2.
#define STEPI(S0,S1,S2, kk) do {                                \
  int L0 = (idx==2)?S0.x:((idx==1)?S0.w:S1.z);                  \
  int L1 = (idx==2)?S0.y:((idx==1)?S1.x:S1.w);                  \
  int L2 = (idx==2)?S0.z:((idx==1)?S1.y:S2.x);                  \
  int v0 = L0-a0, v1 = L1-a1, v2 = L2-a2;                       \
  int bm = v0 > v1 ? v0 : v1; bm = bm > v2 ? bm : v2;           \
  idx = bm & 3;                                                 \
  a0 += (idx==2) ? PEN1 : 0;                                    \
  a1 += (idx==1) ? PEN1 : 0;                                    \
  a2 += (idx==0) ? PEN1 : 0;                                    \
  word |= (unsigned)(2 - idx) << (2*(kk)); } while(0)

__global__ __launch_bounds__(64, 1) void scan6(const int* __restrict__ Lint,
                                               unsigned* __restrict__ curpack){
  __shared__ int lds[TT*12];
  int lane = threadIdx.x;
  for (int i = lane*4; i < TT*12; i += 256)
    *(int4*)&lds[i] = *(const int4*)&Lint[i];
  __syncthreads();
  int a0 = PEN1, a1 = 0, a2 = 0, idx = 2;
  int4 A0,A1,A2,B0,B1,B2,C0,C1,C2,D0,D1,D2,E0,E1,E2,F0,F1,F2,G0,G1,G2,H0,H1,H2;
  LOADI(A0,A1,A2, 0); LOADI(B0,B1,B2, 1); LOADI(C0,C1,C2, 2); LOADI(D0,D1,D2, 3);
  LOADI(E0,E1,E2, 4); LOADI(F0,F1,F2, 5); LOADI(G0,G1,G2, 6); LOADI(H0,H1,H2, 7);
  for (int base = 0; base < 512; base += 16){
    unsigned word = 0u;
    if (base){ STEPI(A0,A1,A2, 0); }            // t=0: cur=0, bits stay 0
    LOADI(A0,A1,A2, base+8);
    STEPI(B0,B1,B2, 1);   LOADI(B0,B1,B2, base+9);
    STEPI(C0,C1,C2, 2);   LOADI(C0,C1,C2, base+10);
    STEPI(D0,D1,D2, 3);   LOADI(D0,D1,D2, base+11);
    STEPI(E0,E1,E2, 4);   LOADI(E0,E1,E2, base+12);
    STEPI(F0,F1,F2, 5);   LOADI(F0,F1,F2, base+13);
    STEPI(G0,G1,G2, 6);   LOADI(G0,G1,G2, base+14);
    STEPI(H0,H1,H2, 7);   LOADI(H0,H1,H2, base+15);
    STEPI(A0,A1,A2, 8);   LOADI(A0,A1,A2, base+16);
    STEPI(B0,B1,B2, 9);   LOADI(B0,B1,B2, base+17);
    STEPI(C0,C1,C2, 10);  LOADI(C0,C1,C2, base+18);
    STEPI(D0,D1,D2, 11);  LOADI(D0,D1,D2, base+19);
    STEPI(E0,E1,E2, 12);  LOADI(E0,E1,E2, base+20);
    STEPI(F0,F1,F2, 13);  LOADI(F0,F1,F2, base+21);
    STEPI(G0,G1,G2, 14);  LOADI(G0,G1,G2, base+22);
    STEPI(H0,H1,H2, 15);  LOADI(H0,H1,H2, base+23);
    if (lane == 0) curpack[base >> 4] = word;
  }
}

// ---------- outputs (f32), fused; cur from 2-bit packed words ----------
__global__ __launch_bounds__(256) void out_all(const float* __restrict__ h_all,
                                               const unsigned* __restrict__ curpack,
                                               float* __restrict__ out){
  int blk = blockIdx.x;
  if (blk < 512){
    int t = blk;
    int cur = (int)((curpack[t >> 4] >> ((t & 15)*2)) & 3u);
    const float* base = h_all + (size_t)cur*98304 + 2*HH;  // [cur][b][2][:], b-stride 1536
    int tid = threadIdx.x;
    for (int k = 0; k < 32; ++k){
      int e4 = (k*256 + tid)*4;                            // [0, 32768)
      int b = e4 >> 9, h = e4 & 511;
      float4 v = *(const float4*)(base + (size_t)b*1536 + h);
      *(float4*)(&out[((size_t)b*TT + t)*HH + h]) = v;
    }
  } else {
    int cur = (int)((curpack[31] >> 30) & 3u);
    int e4 = ((blk - 512)*256 + threadIdx.x)*4;            // [0, 98304)
    float4 v = *(const float4*)(h_all + (size_t)cur*98304 + e4);
    *(float4*)(&out[(size_t)BB*TT*HH + e4]) = v;
  }
}

extern "C" void kernel_launch(void* const* d_in, const int* in_sizes, int n_in,
                              void* d_out, int out_size, void* d_ws, size_t ws_size,
                              hipStream_t stream){
  const float* x    = (const float*)d_in[0];
  const float* Wl   = (const float*)d_in[1];
  // d_in[2] = bl : constant over L inside softmax -> cancels; unused
  const float* Ws   = (const float*)d_in[3];
  const float* bs   = (const float*)d_in[4];
  const float* Wih0 = (const float*)d_in[5];
  const float* bih0 = (const float*)d_in[6];
  const float* bhh0 = (const float*)d_in[7];
  const float* WihL = (const float*)d_in[8];
  const float* bihL = (const float*)d_in[9];
  const float* bhhL = (const float*)d_in[10];
  float* out = (float*)d_out;

  // ---- sentinels ----
  static const int exp_sizes[11] = {8388608, 262144, 512, 2304, 3,
                                    1179648, 4608, 4608, 4718592, 9216, 9216};
  int bad = 0;
  if (n_in != 11) bad = 13;
  else {
    for (int i = 0; i < 11; ++i) if (in_sizes[i] != exp_sizes[i]) { bad = i + 1; break; }
  }
  if (!bad && out_size != 16875520) bad = 12;
  if (bad){
    sentinel_k<<<dim3(1), dim3(1), 0, stream>>>(out, 1048576.0f * (float)bad);
    return;
  }
  if (ws_size < 1292416){
    sentinel_k<<<dim3(1), dim3(1), 0, stream>>>(out, 3.0e7f + (float)(ws_size >> 6));
    return;
  }

  // ---- ws layout ----
  double*   w_d     = (double*)d_ws;              // 512 f64
  double*   score_d = w_d + 512;                  // 576 f64
  double*   dmat_d  = score_d + 576;              // 1728 f64
  int*      Lint    = (int*)(dmat_d + 1728);      // 6144 i32
  float*    h_all   = (float*)(Lint + 6144);      // 294912 f32
  float*    x0T     = h_all + 294912;             // 16384 f32 (unused hole, kept for layout stability)
  unsigned* curpack = (unsigned*)(x0T + 16384);   // 32 u32

  // ---- big scratch in d_out tail (dead before out_all writes) ----
  char* outb = (char*)d_out;
  float* gip = (float*)(outb + 50331648);         // [4][4608][64] f32 = 4,718,592 B
  float* hT0 = gip + 1179648;                     // [3][512][64]  f32 =   393,216 B
  float* hT1 = hT0 + 98304;                       // same

  // GRU stack: K-split partial GEMM + activation (layer 0 self-stages x, + colsum tail)
  gates0x         <<<dim3(584),  dim3(256), 0, stream>>>(x, Wih0, Wl, w_d, gip);
  gru_act<2>      <<<dim3(384),  dim3(256), 0, stream>>>(gip, bih0, G3H, bhh0, G3H, h_all, hT0, 1, 0);
  gates_part2<512><<<dim3(1152), dim3(256), 0, stream>>>(WihL, (long)2*G3H*HH, hT0, HH*BB, gip);
  gru_act<4>      <<<dim3(384),  dim3(256), 0, stream>>>(gip, bihL, 2*G3H, bhhL, 2*G3H, h_all, hT1, 1, 1);
  gates_part2<512><<<dim3(1152), dim3(256), 0, stream>>>(WihL + (size_t)G3H*HH, (long)2*G3H*HH, hT1, HH*BB, gip);
  gru_act<4>      <<<dim3(384),  dim3(256), 0, stream>>>(gip, bihL + G3H, 2*G3H, bhhL + G3H, 2*G3H, h_all, hT0, 0, 2);

  dots2w<<<dim3(576), dim3(256), 0, stream>>>(h_all, w_d, Ws, score_d, dmat_d);
  sums_x<<<dim3(512), dim3(192), 0, stream>>>(x, Ws, score_d, dmat_d, bs, Lint);

  scan6<<<dim3(1), dim3(64), 0, stream>>>(Lint, curpack);

  out_all<<<dim3(608), dim3(256), 0, stream>>>(h_all, curpack, out);
}